// Round 2
// baseline (754.735 us; speedup 1.0000x reference)
//
#include <hip/hip_runtime.h>
#include <hip/hip_bf16.h>
#include <hip/hip_fp16.h>

#define DI __device__ __forceinline__

namespace {

constexpr int G_  = 192;    // 3*H
constexpr int N_  = 128;
constexpr int FT_ = 384;
constexpr int M1_ = 5120;   // B*N*T

DI float lrelu(float x) { return x > 0.f ? x : 0.2f * x; }
DI float sigmoidf(float x) { return 1.f / (1.f + __expf(-x)); }
DI unsigned short f2hu(float x) {
  __half h = __float2half(x);
  union { __half hh; unsigned short u; } cv; cv.hh = h; return cv.u;
}

// ---------------- kernel 1: gx1[k][m][g] = s_[m,k,:] @ sm1_Wi + bi  (fp16 out) ----------
// grid: 800 slabs (b,t,k) x 3 g-tiles = 2400 blocks, 256 threads.
// Each block: out tile [n=128 x g=64], K-loop over FT=384 in chunks of 16 via LDS.
__global__ __launch_bounds__(256) void k_gx1(
    const float* __restrict__ s, const float* __restrict__ Wi,
    const float* __restrict__ bi, __half* __restrict__ gx1) {
  const int bid = blockIdx.x;
  const int slab = bid / 3, gt = bid % 3, g0 = gt * 64;
  const int b = slab / 100, rem = slab % 100, t = rem / 20, k = rem % 20;
  const float* A = s + (size_t)((b * 5 + t) * 20 + k) * (FT_ * N_);  // A[f][n], n contiguous
  __shared__ __align__(16) float As[16][128];
  __shared__ __align__(16) float Bs[16][64];
  const int tid = threadIdx.x;
  const int tn = tid & 31, tj = tid >> 5;   // n-base = tn*4, g-base = tj*8
  float acc[4][8];
#pragma unroll
  for (int i = 0; i < 4; ++i)
#pragma unroll
    for (int j = 0; j < 8; ++j) acc[i][j] = 0.f;

  for (int fc = 0; fc < FT_; fc += 16) {
#pragma unroll
    for (int r = 0; r < 2; ++r) {
      int v = tid + 256 * r;                 // 0..511
      int ff = v >> 5, n4 = (v & 31) << 2;
      *(float4*)&As[ff][n4] = *(const float4*)&A[(size_t)(fc + ff) * N_ + n4];
    }
    {
      int ff = tid >> 4, j4 = (tid & 15) << 2;
      *(float4*)&Bs[ff][j4] = *(const float4*)&Wi[(size_t)(fc + ff) * G_ + g0 + j4];
    }
    __syncthreads();
#pragma unroll
    for (int ff = 0; ff < 16; ++ff) {
      float4 a4 = *(const float4*)&As[ff][tn << 2];
      float4 b0 = *(const float4*)&Bs[ff][tj << 3];
      float4 b1 = *(const float4*)&Bs[ff][(tj << 3) + 4];
      float av[4] = {a4.x, a4.y, a4.z, a4.w};
      float bv[8] = {b0.x, b0.y, b0.z, b0.w, b1.x, b1.y, b1.z, b1.w};
#pragma unroll
      for (int i = 0; i < 4; ++i)
#pragma unroll
        for (int j = 0; j < 8; ++j) acc[i][j] += av[i] * bv[j];
    }
    __syncthreads();
  }
  float biv[8];
#pragma unroll
  for (int j = 0; j < 8; ++j) biv[j] = bi[g0 + (tj << 3) + j];
#pragma unroll
  for (int i = 0; i < 4; ++i) {
    int n = (tn << 2) + i;
    size_t m = (size_t)(b * 128 + n) * 5 + t;          // sequence index (b,n,t)
    size_t row = ((size_t)k * M1_ + m) * G_ + g0 + (tj << 3);
    unsigned int* dst = (unsigned int*)(gx1 + row);    // 16B-aligned (row*2 % 16 == 0)
#pragma unroll
    for (int j2 = 0; j2 < 4; ++j2) {
      unsigned lo = f2hu(acc[i][2 * j2]     + biv[2 * j2]);
      unsigned hi = f2hu(acc[i][2 * j2 + 1] + biv[2 * j2 + 1]);
      dst[j2] = lo | (hi << 16);
    }
  }
}

// ---------------- kernel 2: SM1 GRU scan (20 steps) + temporal attention -> cv ----------
// grid 640, block 192. Thread g owns Wh column g (64 VGPRs). 8 sequences per block.
// State history kept in LDS; attention fused in epilogue (f1 never hits HBM).
__global__ __launch_bounds__(192) void k_scan1(
    const __half* __restrict__ gx1, const float* __restrict__ Wh,
    const float* __restrict__ bh, float* __restrict__ cv) {
  const int s0 = blockIdx.x * 8;
  const int tid = threadIdx.x;
  __shared__ __align__(16) float hist[8][20][64];
  __shared__ float ghl[8][192];
  __shared__ float dls[8][20], als[8][20];
  float whcol[64];
#pragma unroll
  for (int i = 0; i < 64; ++i) whcol[i] = Wh[i * G_ + tid];
  const float bhg = bh[tid];

  for (int k = 0; k < 20; ++k) {
    if (k == 0) {
#pragma unroll
      for (int ss = 0; ss < 8; ++ss) ghl[ss][tid] = bhg;   // h0 = 0 -> gh = bh
    } else {
      for (int ss = 0; ss < 8; ++ss) {
        const float4* hq = (const float4*)&hist[ss][k - 1][0];  // uniform -> LDS broadcast
        float a = 0.f;
#pragma unroll
        for (int q = 0; q < 16; ++q) {
          float4 h4 = hq[q];
          a += h4.x * whcol[4 * q]     + h4.y * whcol[4 * q + 1]
             + h4.z * whcol[4 * q + 2] + h4.w * whcol[4 * q + 3];
        }
        ghl[ss][tid] = a + bhg;
      }
    }
    __syncthreads();
    if (tid < 64) {
      const int i = tid;
      for (int ss = 0; ss < 8; ++ss) {
        size_t base = ((size_t)k * M1_ + (s0 + ss)) * G_;
        float xr = __half2float(gx1[base + i]);
        float xz = __half2float(gx1[base + 64 + i]);
        float xn = __half2float(gx1[base + 128 + i]);
        float hr = ghl[ss][i], hz = ghl[ss][64 + i], hn = ghl[ss][128 + i];
        float r  = sigmoidf(xr + hr);
        float z  = sigmoidf(xz + hz);
        float nn = tanhf(xn + r * hn);
        float hp = (k == 0) ? 0.f : hist[ss][k - 1][i];
        hist[ss][k][i] = (1.f - z) * nn + z * hp;
      }
    }
    __syncthreads();
  }
  // temporal attention: a = softmax_k(f1_k . last); cv = sum a_k f1_k
  if (tid < 160) {
    int ss = tid / 20, kk = tid % 20;
    float d = 0.f;
#pragma unroll
    for (int i = 0; i < 64; ++i) d += hist[ss][kk][i] * hist[ss][19][i];
    dls[ss][kk] = d;
  }
  __syncthreads();
  if (tid < 160) {
    int ss = tid / 20, kk = tid % 20;
    float mx = -3.4e38f;
#pragma unroll
    for (int j = 0; j < 20; ++j) mx = fmaxf(mx, dls[ss][j]);
    als[ss][kk] = __expf(dls[ss][kk] - mx);
  }
  __syncthreads();
  for (int idx = tid; idx < 512; idx += 192) {
    int ss = idx >> 6, i = idx & 63;
    float sum = 0.f, a = 0.f;
#pragma unroll
    for (int kk = 0; kk < 20; ++kk) sum += als[ss][kk];
#pragma unroll
    for (int kk = 0; kk < 20; ++kk) a += als[ss][kk] * hist[ss][kk][i];
    cv[(size_t)(s0 + ss) * 64 + i] = a / sum;
  }
}

// ---------------- kernel 3: SM2 GRU (5 steps, input 64) + attention -> ct ----------
__global__ __launch_bounds__(192) void k_scan2(
    const float* __restrict__ x, const float* __restrict__ Wi,
    const float* __restrict__ Wh, const float* __restrict__ bi,
    const float* __restrict__ bh, float* __restrict__ outv) {
  const int s0 = blockIdx.x * 8;
  const int tid = threadIdx.x;
  __shared__ __align__(16) float hist[8][5][64];
  __shared__ __align__(16) float xl[8][64];
  __shared__ float ghl[8][192], gxl[8][192];
  __shared__ float dls[8][5], als[8][5];
  float wic[64], whc[64];
#pragma unroll
  for (int i = 0; i < 64; ++i) { wic[i] = Wi[i * G_ + tid]; whc[i] = Wh[i * G_ + tid]; }
  const float big = bi[tid], bhg = bh[tid];

  for (int t = 0; t < 5; ++t) {
    for (int v = tid; v < 512; v += 192) {
      int ss = v >> 6, i = v & 63;
      xl[ss][i] = x[((size_t)(s0 + ss) * 5 + t) * 64 + i];
    }
    __syncthreads();
    for (int ss = 0; ss < 8; ++ss) {
      const float4* xq = (const float4*)&xl[ss][0];
      float ax = 0.f;
#pragma unroll
      for (int q = 0; q < 16; ++q) {
        float4 v4 = xq[q];
        ax += v4.x * wic[4 * q]     + v4.y * wic[4 * q + 1]
            + v4.z * wic[4 * q + 2] + v4.w * wic[4 * q + 3];
      }
      gxl[ss][tid] = ax + big;
      float ah = 0.f;
      if (t > 0) {
        const float4* hq = (const float4*)&hist[ss][t - 1][0];
#pragma unroll
        for (int q = 0; q < 16; ++q) {
          float4 h4 = hq[q];
          ah += h4.x * whc[4 * q]     + h4.y * whc[4 * q + 1]
              + h4.z * whc[4 * q + 2] + h4.w * whc[4 * q + 3];
        }
      }
      ghl[ss][tid] = ah + bhg;
    }
    __syncthreads();
    if (tid < 64) {
      const int i = tid;
      for (int ss = 0; ss < 8; ++ss) {
        float xr = gxl[ss][i], xz = gxl[ss][64 + i], xn = gxl[ss][128 + i];
        float hr = ghl[ss][i], hz = ghl[ss][64 + i], hn = ghl[ss][128 + i];
        float r  = sigmoidf(xr + hr);
        float z  = sigmoidf(xz + hz);
        float nn = tanhf(xn + r * hn);
        float hp = (t == 0) ? 0.f : hist[ss][t - 1][i];
        hist[ss][t][i] = (1.f - z) * nn + z * hp;
      }
    }
    __syncthreads();
  }
  if (tid < 40) {
    int ss = tid / 5, kk = tid % 5;
    float d = 0.f;
#pragma unroll
    for (int i = 0; i < 64; ++i) d += hist[ss][kk][i] * hist[ss][4][i];
    dls[ss][kk] = d;
  }
  __syncthreads();
  if (tid < 40) {
    int ss = tid / 5, kk = tid % 5;
    float mx = -3.4e38f;
#pragma unroll
    for (int j = 0; j < 5; ++j) mx = fmaxf(mx, dls[ss][j]);
    als[ss][kk] = __expf(dls[ss][kk] - mx);
  }
  __syncthreads();
  for (int idx = tid; idx < 512; idx += 192) {
    int ss = idx >> 6, i = idx & 63;
    float sum = 0.f, a = 0.f;
#pragma unroll
    for (int kk = 0; kk < 5; ++kk) sum += als[ss][kk];
#pragma unroll
    for (int kk = 0; kk < 5; ++kk) a += als[ss][kk] * hist[ss][kk][i];
    outv[(size_t)(s0 + ss) * 64 + i] = a / sum;
  }
}

// ---------------- kernel 4: price GRU (input dim 3, gx fused) + attention -> qt ----------
__global__ __launch_bounds__(192) void k_scan3(
    const float* __restrict__ p, const float* __restrict__ Wi,
    const float* __restrict__ Wh, const float* __restrict__ bi,
    const float* __restrict__ bh, float* __restrict__ outv) {
  const int s0 = blockIdx.x * 8;
  const int tid = threadIdx.x;
  __shared__ __align__(16) float hist[8][5][64];
  __shared__ float xp[8][3];
  __shared__ float ghl[8][192], gxl[8][192];
  __shared__ float dls[8][5], als[8][5];
  float wic[3], whc[64];
#pragma unroll
  for (int f = 0; f < 3; ++f) wic[f] = Wi[f * G_ + tid];
#pragma unroll
  for (int i = 0; i < 64; ++i) whc[i] = Wh[i * G_ + tid];
  const float big = bi[tid], bhg = bh[tid];

  for (int t = 0; t < 5; ++t) {
    if (tid < 24) {
      int ss = tid / 3, f = tid % 3;
      int seq = s0 + ss, b = seq >> 7, n = seq & 127;
      xp[ss][f] = p[((size_t)(b * 5 + t) * 3 + f) * 128 + n];
    }
    __syncthreads();
    for (int ss = 0; ss < 8; ++ss) {
      gxl[ss][tid] = xp[ss][0] * wic[0] + xp[ss][1] * wic[1] + xp[ss][2] * wic[2] + big;
      float ah = 0.f;
      if (t > 0) {
        const float4* hq = (const float4*)&hist[ss][t - 1][0];
#pragma unroll
        for (int q = 0; q < 16; ++q) {
          float4 h4 = hq[q];
          ah += h4.x * whc[4 * q]     + h4.y * whc[4 * q + 1]
              + h4.z * whc[4 * q + 2] + h4.w * whc[4 * q + 3];
        }
      }
      ghl[ss][tid] = ah + bhg;
    }
    __syncthreads();
    if (tid < 64) {
      const int i = tid;
      for (int ss = 0; ss < 8; ++ss) {
        float xr = gxl[ss][i], xz = gxl[ss][64 + i], xn = gxl[ss][128 + i];
        float hr = ghl[ss][i], hz = ghl[ss][64 + i], hn = ghl[ss][128 + i];
        float r  = sigmoidf(xr + hr);
        float z  = sigmoidf(xz + hz);
        float nn = tanhf(xn + r * hn);
        float hp = (t == 0) ? 0.f : hist[ss][t - 1][i];
        hist[ss][t][i] = (1.f - z) * nn + z * hp;
      }
    }
    __syncthreads();
  }
  if (tid < 40) {
    int ss = tid / 5, kk = tid % 5;
    float d = 0.f;
#pragma unroll
    for (int i = 0; i < 64; ++i) d += hist[ss][kk][i] * hist[ss][4][i];
    dls[ss][kk] = d;
  }
  __syncthreads();
  if (tid < 40) {
    int ss = tid / 5, kk = tid % 5;
    float mx = -3.4e38f;
#pragma unroll
    for (int j = 0; j < 5; ++j) mx = fmaxf(mx, dls[ss][j]);
    als[ss][kk] = __expf(dls[ss][kk] - mx);
  }
  __syncthreads();
  for (int idx = tid; idx < 512; idx += 192) {
    int ss = idx >> 6, i = idx & 63;
    float sum = 0.f, a = 0.f;
#pragma unroll
    for (int kk = 0; kk < 5; ++kk) sum += als[ss][kk];
#pragma unroll
    for (int kk = 0; kk < 5; ++kk) a += als[ss][kk] * hist[ss][kk][i];
    outv[(size_t)(s0 + ss) * 64 + i] = a / sum;
  }
}

// ---------------- kernel 5: bilinear fusion X = tanh(ct . Wb . qt + bb) ----------
// 4 (b,n) pairs per block; thread = (o, j-quarter); qt slice held in registers.
__global__ __launch_bounds__(256) void k_bilinear(
    const float* __restrict__ ct, const float* __restrict__ qt,
    const float* __restrict__ Wb, const float* __restrict__ bb,
    float* __restrict__ X) {
  const int bn0 = blockIdx.x * 4;
  const int tid = threadIdx.x;
  __shared__ float ctl[4][64], qtl[4][64];
  {
    int ss = tid >> 6, i = tid & 63;
    ctl[ss][i] = ct[(size_t)(bn0 + ss) * 64 + i];
    qtl[ss][i] = qt[(size_t)(bn0 + ss) * 64 + i];
  }
  __syncthreads();
  const int o = tid >> 2, part = tid & 3, j0 = part << 4;
  float qr[4][16];
#pragma unroll
  for (int pp = 0; pp < 4; ++pp)
#pragma unroll
    for (int q = 0; q < 16; ++q) qr[pp][q] = qtl[pp][j0 + q];
  float acc[4] = {0.f, 0.f, 0.f, 0.f};
  const float* wb = Wb + (size_t)o * 4096 + j0;
  for (int i = 0; i < 64; ++i) {
    const float4* w4 = (const float4*)(wb + i * 64);
    float tmp[4] = {0.f, 0.f, 0.f, 0.f};
#pragma unroll
    for (int q = 0; q < 4; ++q) {
      float4 w = w4[q];
#pragma unroll
      for (int pp = 0; pp < 4; ++pp)
        tmp[pp] += w.x * qr[pp][4 * q]     + w.y * qr[pp][4 * q + 1]
                 + w.z * qr[pp][4 * q + 2] + w.w * qr[pp][4 * q + 3];
    }
#pragma unroll
    for (int pp = 0; pp < 4; ++pp) acc[pp] += ctl[pp][i] * tmp[pp];
  }
#pragma unroll
  for (int pp = 0; pp < 4; ++pp) {
    acc[pp] += __shfl_xor(acc[pp], 1);
    acc[pp] += __shfl_xor(acc[pp], 2);
  }
  if (part == 0) {
    float bbv = bb[o];
#pragma unroll
    for (int pp = 0; pp < 4; ++pp)
      X[(size_t)(bn0 + pp) * 64 + o] = tanhf(acc[pp] + bbv);
  }
}

// ---------------- kernel 6: GAT layer 1 fully fused per (b, head) ----------
__global__ __launch_bounds__(256) void k_gat1(
    const float* __restrict__ X, const float* __restrict__ W1,
    const float* __restrict__ a1, const float* __restrict__ adj,
    float* __restrict__ X2) {
  const int b = blockIdx.x >> 3, k = blockIdx.x & 7;
  const int tid = threadIdx.x;
  __shared__ __align__(16) float whd[128][68];   // stride 68 -> 16B aligned rows, few conflicts
  __shared__ float w1l[64][64];
  __shared__ float d1l[128], d2l[128];
  for (int v = tid; v < 4096; v += 256) w1l[v >> 6][v & 63] = W1[(size_t)k * 4096 + v];
  __syncthreads();
  {
    const int f = tid & 63, ng = tid >> 6;       // wave-uniform ng
    const float* Xb = X + (size_t)b * 128 * 64;
    for (int n = ng * 32; n < ng * 32 + 32; ++n) {
      float a = 0.f;
#pragma unroll
      for (int h = 0; h < 64; ++h) a += Xb[n * 64 + h] * w1l[h][f];
      whd[n][f] = a;
    }
  }
  __syncthreads();
  if (tid < 128) {
    const int n = tid;
    float da = 0.f, db = 0.f;
#pragma unroll
    for (int f = 0; f < 64; ++f) {
      float w = whd[n][f];
      da += w * a1[k * 128 + f];
      db += w * a1[k * 128 + 64 + f];
    }
    d1l[n] = da; d2l[n] = db;
  }
  __syncthreads();
  {
    const int n = tid & 127, fh = tid >> 7;
    unsigned long long mlo = 0ull, mhi = 0ull;
    for (int m = 0; m < 64; ++m) if (adj[n * 128 + m] > 0.f)      mlo |= (1ull << m);
    for (int m = 0; m < 64; ++m) if (adj[n * 128 + 64 + m] > 0.f) mhi |= (1ull << m);
    const float d1n = d1l[n];
    float mx = -3.4e38f;
    for (int m = 0; m < 128; ++m) {
      bool on = (m < 64) ? (((mlo >> m) & 1ull) != 0) : (((mhi >> (m - 64)) & 1ull) != 0);
      float e = lrelu(d1n + d2l[m]);
      mx = fmaxf(mx, on ? e : -3.4e38f);
    }
    float sum = 0.f;
    float acc[32];
#pragma unroll
    for (int q = 0; q < 32; ++q) acc[q] = 0.f;
    for (int m = 0; m < 128; ++m) {
      bool on = (m < 64) ? (((mlo >> m) & 1ull) != 0) : (((mhi >> (m - 64)) & 1ull) != 0);
      float w = on ? __expf(lrelu(d1n + d2l[m]) - mx) : 0.f;
      sum += w;
      const float4* wr = (const float4*)&whd[m][fh * 32];
#pragma unroll
      for (int q8 = 0; q8 < 8; ++q8) {
        float4 wv = wr[q8];
        acc[4 * q8]     += w * wv.x;
        acc[4 * q8 + 1] += w * wv.y;
        acc[4 * q8 + 2] += w * wv.z;
        acc[4 * q8 + 3] += w * wv.w;
      }
    }
    float inv = 1.f / sum;
    float* dst = X2 + ((size_t)b * 128 + n) * 512 + k * 64 + fh * 32;
#pragma unroll
    for (int q = 0; q < 32; ++q) {
      float v = acc[q] * inv;
      dst[q] = v > 0.f ? v : (__expf(v) - 1.f);   // elu
    }
  }
}

// ---------------- kernel 7: per-(b,n): out1 head, Wh2 = X2@W2, a2 dots ----------
__global__ __launch_bounds__(256) void k_pern(
    const float* __restrict__ X, const float* __restrict__ Wx, const float* __restrict__ bx,
    const float* __restrict__ X2, const float* __restrict__ W2, const float* __restrict__ a2,
    float* __restrict__ out1, float* __restrict__ Wh2,
    float* __restrict__ d2a, float* __restrict__ d2b) {
  const int bn = blockIdx.x * 256 + threadIdx.x;   // 0..1023
  const int n = bn & 127;
#pragma unroll
  for (int c = 0; c < 2; ++c) {
    float a = 0.f;
#pragma unroll
    for (int h = 0; h < 64; ++h) a += X[(size_t)bn * 64 + h] * Wx[(n * 2 + c) * 64 + h];
    out1[bn * 2 + c] = tanhf(a + bx[n * 2 + c]);
  }
  float w0 = 0.f, w1 = 0.f;
  const float* xr = X2 + (size_t)bn * 512;
  for (int g = 0; g < 512; ++g) { float xv = xr[g]; w0 += xv * W2[g * 2]; w1 += xv * W2[g * 2 + 1]; }
  Wh2[bn * 2] = w0; Wh2[bn * 2 + 1] = w1;
  d2a[bn] = w0 * a2[0] + w1 * a2[1];
  d2b[bn] = w0 * a2[2] + w1 * a2[3];
}

// ---------------- kernel 8: GAT layer 2 softmax + residual -> fp32 out [B,C,N] ----------
__global__ __launch_bounds__(128) void k_final(
    const float* __restrict__ adj, const float* __restrict__ Wh2,
    const float* __restrict__ d2a, const float* __restrict__ d2b,
    const float* __restrict__ out1, float* __restrict__ out) {
  const int b = blockIdx.x;
  const int tid = threadIdx.x;    // n
  __shared__ float wh2l[128][2];
  __shared__ float dbl_[128];
  wh2l[tid][0] = Wh2[(size_t)(b * 128 + tid) * 2];
  wh2l[tid][1] = Wh2[(size_t)(b * 128 + tid) * 2 + 1];
  dbl_[tid] = d2b[b * 128 + tid];
  __syncthreads();
  const int n = tid;
  unsigned long long mlo = 0ull, mhi = 0ull;
  for (int m = 0; m < 64; ++m) if (adj[n * 128 + m] > 0.f)      mlo |= (1ull << m);
  for (int m = 0; m < 64; ++m) if (adj[n * 128 + 64 + m] > 0.f) mhi |= (1ull << m);
  const float dan = d2a[b * 128 + n];
  float mx = -3.4e38f;
  for (int m = 0; m < 128; ++m) {
    bool on = (m < 64) ? (((mlo >> m) & 1ull) != 0) : (((mhi >> (m - 64)) & 1ull) != 0);
    float e = lrelu(dan + dbl_[m]);
    mx = fmaxf(mx, on ? e : -3.4e38f);
  }
  float sum = 0.f, x0 = 0.f, x1 = 0.f;
  for (int m = 0; m < 128; ++m) {
    bool on = (m < 64) ? (((mlo >> m) & 1ull) != 0) : (((mhi >> (m - 64)) & 1ull) != 0);
    float w = on ? __expf(lrelu(dan + dbl_[m]) - mx) : 0.f;
    sum += w; x0 += w * wh2l[m][0]; x1 += w * wh2l[m][1];
  }
  float inv = 1.f / sum;
  float o0 = x0 * inv + out1[(size_t)(b * 128 + n) * 2];
  float o1 = x1 * inv + out1[(size_t)(b * 128 + n) * 2 + 1];
  out[(size_t)(b * 2 + 0) * 128 + n] = o0;
  out[(size_t)(b * 2 + 1) * 128 + n] = o1;
}

} // namespace

extern "C" void kernel_launch(void* const* d_in, const int* in_sizes, int n_in,
                              void* d_out, int out_size, void* d_ws, size_t ws_size,
                              hipStream_t stream) {
  (void)in_sizes; (void)n_in; (void)out_size;
  const float* s      = (const float*)d_in[0];
  const float* p      = (const float*)d_in[1];
  const float* adj    = (const float*)d_in[2];
  const float* sm1_Wi = (const float*)d_in[3];
  const float* sm1_Wh = (const float*)d_in[4];
  const float* sm1_bi = (const float*)d_in[5];
  const float* sm1_bh = (const float*)d_in[6];
  const float* sm2_Wi = (const float*)d_in[7];
  const float* sm2_Wh = (const float*)d_in[8];
  const float* sm2_bi = (const float*)d_in[9];
  const float* sm2_bh = (const float*)d_in[10];
  const float* pr_Wi  = (const float*)d_in[11];
  const float* pr_Wh  = (const float*)d_in[12];
  const float* pr_bi  = (const float*)d_in[13];
  const float* pr_bh  = (const float*)d_in[14];
  const float* Wb     = (const float*)d_in[15];
  const float* bb     = (const float*)d_in[16];
  const float* Wx     = (const float*)d_in[17];
  const float* bx     = (const float*)d_in[18];
  const float* W1     = (const float*)d_in[19];
  const float* a1     = (const float*)d_in[20];
  const float* W2     = (const float*)d_in[21];
  const float* a2     = (const float*)d_in[22];

  // workspace layout (bytes); total = 43,540,480
  if (ws_size < 43540480u) return;
  char* ws = (char*)d_ws;
  __half* gx1 = (__half*)ws;                            // 20*5120*192 fp16 = 39,321,600 B
  float* cv   = (float*)(ws + 39321600);                // 5120*64
  float* ct   = (float*)(ws + 40632320);                // 1024*64
  float* qt   = (float*)(ws + 40894464);                // 1024*64
  float* X    = (float*)(ws + 41156608);                // 1024*64
  float* out1 = (float*)(ws + 41418752);                // 1024*2
  float* X2   = (float*)(ws + 41426944);                // 8*128*512
  float* Wh2  = (float*)(ws + 43524096);                // 1024*2
  float* d2a  = (float*)(ws + 43532288);                // 1024
  float* d2b  = (float*)(ws + 43536384);                // 1024

  hipLaunchKernelGGL(k_gx1,      dim3(2400), dim3(256), 0, stream, s, sm1_Wi, sm1_bi, gx1);
  hipLaunchKernelGGL(k_scan1,    dim3(640),  dim3(192), 0, stream, gx1, sm1_Wh, sm1_bh, cv);
  hipLaunchKernelGGL(k_scan2,    dim3(128),  dim3(192), 0, stream, cv, sm2_Wi, sm2_Wh, sm2_bi, sm2_bh, ct);
  hipLaunchKernelGGL(k_scan3,    dim3(128),  dim3(192), 0, stream, p, pr_Wi, pr_Wh, pr_bi, pr_bh, qt);
  hipLaunchKernelGGL(k_bilinear, dim3(256),  dim3(256), 0, stream, ct, qt, Wb, bb, X);
  hipLaunchKernelGGL(k_gat1,     dim3(64),   dim3(256), 0, stream, X, W1, a1, adj, X2);
  hipLaunchKernelGGL(k_pern,     dim3(4),    dim3(256), 0, stream, X, Wx, bx, X2, W2, a2, out1, Wh2, d2a, d2b);
  hipLaunchKernelGGL(k_final,    dim3(8),    dim3(128), 0, stream, adj, Wh2, d2a, d2b, out1, (float*)d_out);
}

// Round 3
// 553.381 us; speedup vs baseline: 1.3639x; 1.3639x over previous
//
#include <hip/hip_runtime.h>
#include <hip/hip_bf16.h>
#include <hip/hip_fp16.h>

#define DI __device__ __forceinline__

namespace {

constexpr int G_  = 192;    // 3*H
constexpr int FT_ = 384;
constexpr int M1_ = 5120;   // B*N*T

typedef _Float16 f16x8 __attribute__((ext_vector_type(8)));
typedef _Float16 f16x4 __attribute__((ext_vector_type(4)));
typedef float    f32x4 __attribute__((ext_vector_type(4)));

DI float lrelu(float x) { return x > 0.f ? x : 0.2f * x; }
DI float sigmoidf(float x) { return 1.f / (1.f + __expf(-x)); }
DI float tanh_fast(float x) { float e = __expf(2.f * x); return 1.f - 2.f / (e + 1.f); }

// ---------------- kernel 0: Bt[g][f] = fp16(Wi[f][g]) ----------
__global__ __launch_bounds__(256) void k_cvtB(
    const float* __restrict__ Wi, _Float16* __restrict__ Bt) {
  int v = blockIdx.x * 256 + threadIdx.x;   // 73728 = 192*384
  int g = v / 384, f = v % 384;
  Bt[v] = (_Float16)Wi[f * 192 + g];
}

// ---------------- kernel 1: gx1 = s_slab^T @ Wi + bi via fp16 MFMA ----------
// 1 block per slab (b,t,k): out [128 n][192 g]; C^T form: MFMA M=g, N=n, K=f.
__global__ __launch_bounds__(256) void k_gx1(
    const float* __restrict__ s, const _Float16* __restrict__ Bt,
    const float* __restrict__ bi, __half* __restrict__ gx1) {
  const int slab = blockIdx.x;
  const int b = slab / 100, rem = slab % 100, t = rem / 20, k = rem % 20;
  const float* A = s + (size_t)((b * 5 + t) * 20 + k) * (FT_ * 128);  // [f][n]
  __shared__ __align__(16) _Float16 AsL[128 * 40];   // [n][k'] rows padded to 40 halves
  __shared__ __align__(16) _Float16 BsL[192 * 40];   // [g][k']
  __shared__ float bisL[192];
  const int tid = threadIdx.x;
  if (tid < 192) bisL[tid] = bi[tid];
  const int w = tid >> 6, l = tid & 63;
  const int lr = l & 15, lk = l >> 4;     // row-in-tile / k-octet

  f32x4 acc[12][2];
#pragma unroll
  for (int gt = 0; gt < 12; ++gt)
#pragma unroll
    for (int nt = 0; nt < 2; ++nt) acc[gt][nt] = (f32x4){0.f, 0.f, 0.f, 0.f};

  for (int kc = 0; kc < 12; ++kc) {
    const int f0 = kc * 32;
    // stage A: 4 k-octets x 128 n  (transpose f->row-contiguous)
#pragma unroll
    for (int pass = 0; pass < 2; ++pass) {
      int task = tid + 256 * pass;
      int n = task & 127, oct = task >> 7;          // oct 0..3
      const float* src = A + (size_t)(f0 + oct * 8) * 128 + n;
      float v[8];
#pragma unroll
      for (int j = 0; j < 8; ++j) v[j] = src[j * 128];
      f16x8 h;
#pragma unroll
      for (int j = 0; j < 8; ++j) h[j] = (_Float16)v[j];
      *(f16x8*)&AsL[n * 40 + oct * 8] = h;
    }
    // stage B: copy Bt[g][f0..f0+31]
#pragma unroll
    for (int pass = 0; pass < 3; ++pass) {
      int c = tid + 256 * pass;
      int g = c >> 2, oct = c & 3;
      f16x8 h = *(const f16x8*)&Bt[(size_t)g * 384 + f0 + oct * 8];
      *(f16x8*)&BsL[g * 40 + oct * 8] = h;
    }
    __syncthreads();
    f16x8 aN[2];
#pragma unroll
    for (int nt = 0; nt < 2; ++nt)
      aN[nt] = *(const f16x8*)&AsL[(w * 32 + nt * 16 + lr) * 40 + lk * 8];
#pragma unroll
    for (int gt = 0; gt < 12; ++gt) {
      f16x8 bW = *(const f16x8*)&BsL[(gt * 16 + lr) * 40 + lk * 8];
      acc[gt][0] = __builtin_amdgcn_mfma_f32_16x16x32_f16(bW, aN[0], acc[gt][0], 0, 0, 0);
      acc[gt][1] = __builtin_amdgcn_mfma_f32_16x16x32_f16(bW, aN[1], acc[gt][1], 0, 0, 0);
    }
    __syncthreads();
  }
  // epilogue: lane l reg r -> g = gt*16 + lk*4 + r, n = w*32 + nt*16 + lr
#pragma unroll
  for (int nt = 0; nt < 2; ++nt) {
    int n = w * 32 + nt * 16 + lr;
    size_t m = (size_t)(b * 128 + n) * 5 + t;
    _Float16* dst = (_Float16*)gx1 + ((size_t)k * M1_ + m) * G_;
#pragma unroll
    for (int gt = 0; gt < 12; ++gt) {
      int gq = gt * 16 + lk * 4;
      float4 bias = *(const float4*)&bisL[gq];
      f32x4 c = acc[gt][nt];
      f16x4 h;
      h[0] = (_Float16)(c[0] + bias.x);
      h[1] = (_Float16)(c[1] + bias.y);
      h[2] = (_Float16)(c[2] + bias.z);
      h[3] = (_Float16)(c[3] + bias.w);
      *(f16x4*)&dst[gq] = h;
    }
  }
}

// ---------------- kernel 2: SM1 GRU scan (20 steps) + temporal attention -> cv ----------
__global__ __launch_bounds__(192) void k_scan1(
    const __half* __restrict__ gx1, const float* __restrict__ Wh,
    const float* __restrict__ bh, float* __restrict__ cv) {
  const int s0 = blockIdx.x * 8;
  const int tid = threadIdx.x;
  __shared__ __align__(16) float hist[8][20][64];
  __shared__ float ghl[8][192];
  __shared__ float dls[8][20], als[8][20];
  float whcol[64];
#pragma unroll
  for (int i = 0; i < 64; ++i) whcol[i] = Wh[i * G_ + tid];
  const float bhg = bh[tid];

  for (int k = 0; k < 20; ++k) {
    if (k == 0) {
#pragma unroll
      for (int ss = 0; ss < 8; ++ss) ghl[ss][tid] = bhg;
    } else {
#pragma unroll
      for (int ss = 0; ss < 8; ++ss) {
        const float4* hq = (const float4*)&hist[ss][k - 1][0];
        float a = 0.f;
#pragma unroll
        for (int q = 0; q < 16; ++q) {
          float4 h4 = hq[q];
          a += h4.x * whcol[4 * q]     + h4.y * whcol[4 * q + 1]
             + h4.z * whcol[4 * q + 2] + h4.w * whcol[4 * q + 3];
        }
        ghl[ss][tid] = a + bhg;
      }
    }
    __syncthreads();
    // phase 2: 512 gate tasks across all 192 threads
#pragma unroll
    for (int base = 0; base < 512; base += 192) {
      int task = base + tid;
      if (task < 512) {
        int ss = task >> 6, i = task & 63;
        size_t gbase = ((size_t)k * M1_ + (s0 + ss)) * G_;
        float xr = __half2float(gx1[gbase + i]);
        float xz = __half2float(gx1[gbase + 64 + i]);
        float xn = __half2float(gx1[gbase + 128 + i]);
        float hr = ghl[ss][i], hz = ghl[ss][64 + i], hn = ghl[ss][128 + i];
        float r  = sigmoidf(xr + hr);
        float z  = sigmoidf(xz + hz);
        float nn = tanh_fast(xn + r * hn);
        float hp = (k == 0) ? 0.f : hist[ss][k - 1][i];
        hist[ss][k][i] = (1.f - z) * nn + z * hp;
      }
    }
    __syncthreads();
  }
  if (tid < 160) {
    int ss = tid / 20, kk = tid % 20;
    float d = 0.f;
#pragma unroll
    for (int i = 0; i < 64; ++i) d += hist[ss][kk][i] * hist[ss][19][i];
    dls[ss][kk] = d;
  }
  __syncthreads();
  if (tid < 160) {
    int ss = tid / 20, kk = tid % 20;
    float mx = -3.4e38f;
#pragma unroll
    for (int j = 0; j < 20; ++j) mx = fmaxf(mx, dls[ss][j]);
    als[ss][kk] = __expf(dls[ss][kk] - mx);
  }
  __syncthreads();
  for (int idx = tid; idx < 512; idx += 192) {
    int ss = idx >> 6, i = idx & 63;
    float sum = 0.f, a = 0.f;
#pragma unroll
    for (int kk = 0; kk < 20; ++kk) sum += als[ss][kk];
#pragma unroll
    for (int kk = 0; kk < 20; ++kk) a += als[ss][kk] * hist[ss][kk][i];
    cv[(size_t)(s0 + ss) * 64 + i] = a / sum;
  }
}

// ---------------- kernel 3: SM2 GRU (5 steps, input 64) + attention -> ct (4 seq/block) ----------
__global__ __launch_bounds__(192) void k_scan2(
    const float* __restrict__ x, const float* __restrict__ Wi,
    const float* __restrict__ Wh, const float* __restrict__ bi,
    const float* __restrict__ bh, float* __restrict__ outv) {
  const int s0 = blockIdx.x * 4;
  const int tid = threadIdx.x;
  __shared__ __align__(16) float hist[4][5][64];
  __shared__ __align__(16) float xl[4][64];
  __shared__ float ghl[4][192], gxl[4][192];
  __shared__ float dls[4][5], als[4][5];
  float wic[64], whc[64];
#pragma unroll
  for (int i = 0; i < 64; ++i) { wic[i] = Wi[i * G_ + tid]; whc[i] = Wh[i * G_ + tid]; }
  const float big = bi[tid], bhg = bh[tid];

  for (int t = 0; t < 5; ++t) {
    for (int v = tid; v < 256; v += 192) {
      int ss = v >> 6, i = v & 63;
      xl[ss][i] = x[((size_t)(s0 + ss) * 5 + t) * 64 + i];
    }
    __syncthreads();
#pragma unroll
    for (int ss = 0; ss < 4; ++ss) {
      const float4* xq = (const float4*)&xl[ss][0];
      float ax = 0.f;
#pragma unroll
      for (int q = 0; q < 16; ++q) {
        float4 v4 = xq[q];
        ax += v4.x * wic[4 * q]     + v4.y * wic[4 * q + 1]
            + v4.z * wic[4 * q + 2] + v4.w * wic[4 * q + 3];
      }
      gxl[ss][tid] = ax + big;
      float ah = 0.f;
      if (t > 0) {
        const float4* hq = (const float4*)&hist[ss][t - 1][0];
#pragma unroll
        for (int q = 0; q < 16; ++q) {
          float4 h4 = hq[q];
          ah += h4.x * whc[4 * q]     + h4.y * whc[4 * q + 1]
              + h4.z * whc[4 * q + 2] + h4.w * whc[4 * q + 3];
        }
      }
      ghl[ss][tid] = ah + bhg;
    }
    __syncthreads();
    {
      int task = tid;                      // 256 tasks over 192 threads: 2 passes
#pragma unroll
      for (int base = 0; base < 256; base += 192) {
        int tk = base + tid;
        if (tk < 256) {
          int ss = tk >> 6, i = tk & 63;
          float xr = gxl[ss][i], xz = gxl[ss][64 + i], xn = gxl[ss][128 + i];
          float hr = ghl[ss][i], hz = ghl[ss][64 + i], hn = ghl[ss][128 + i];
          float r  = sigmoidf(xr + hr);
          float z  = sigmoidf(xz + hz);
          float nn = tanh_fast(xn + r * hn);
          float hp = (t == 0) ? 0.f : hist[ss][t - 1][i];
          hist[ss][t][i] = (1.f - z) * nn + z * hp;
        }
      }
      (void)task;
    }
    __syncthreads();
  }
  if (tid < 20) {
    int ss = tid / 5, kk = tid % 5;
    float d = 0.f;
#pragma unroll
    for (int i = 0; i < 64; ++i) d += hist[ss][kk][i] * hist[ss][4][i];
    dls[ss][kk] = d;
  }
  __syncthreads();
  if (tid < 20) {
    int ss = tid / 5, kk = tid % 5;
    float mx = -3.4e38f;
#pragma unroll
    for (int j = 0; j < 5; ++j) mx = fmaxf(mx, dls[ss][j]);
    als[ss][kk] = __expf(dls[ss][kk] - mx);
  }
  __syncthreads();
  for (int idx = tid; idx < 256; idx += 192) {
    int ss = idx >> 6, i = idx & 63;
    float sum = 0.f, a = 0.f;
#pragma unroll
    for (int kk = 0; kk < 5; ++kk) sum += als[ss][kk];
#pragma unroll
    for (int kk = 0; kk < 5; ++kk) a += als[ss][kk] * hist[ss][kk][i];
    outv[(size_t)(s0 + ss) * 64 + i] = a / sum;
  }
}

// ---------------- kernel 4: price GRU (input dim 3) + attention -> qt (4 seq/block) ----------
__global__ __launch_bounds__(192) void k_scan3(
    const float* __restrict__ p, const float* __restrict__ Wi,
    const float* __restrict__ Wh, const float* __restrict__ bi,
    const float* __restrict__ bh, float* __restrict__ outv) {
  const int s0 = blockIdx.x * 4;
  const int tid = threadIdx.x;
  __shared__ __align__(16) float hist[4][5][64];
  __shared__ float xp[4][3];
  __shared__ float ghl[4][192], gxl[4][192];
  __shared__ float dls[4][5], als[4][5];
  float wic[3], whc[64];
#pragma unroll
  for (int f = 0; f < 3; ++f) wic[f] = Wi[f * G_ + tid];
#pragma unroll
  for (int i = 0; i < 64; ++i) whc[i] = Wh[i * G_ + tid];
  const float big = bi[tid], bhg = bh[tid];

  for (int t = 0; t < 5; ++t) {
    if (tid < 12) {
      int ss = tid / 3, f = tid % 3;
      int seq = s0 + ss, b = seq >> 7, n = seq & 127;
      xp[ss][f] = p[((size_t)(b * 5 + t) * 3 + f) * 128 + n];
    }
    __syncthreads();
#pragma unroll
    for (int ss = 0; ss < 4; ++ss) {
      gxl[ss][tid] = xp[ss][0] * wic[0] + xp[ss][1] * wic[1] + xp[ss][2] * wic[2] + big;
      float ah = 0.f;
      if (t > 0) {
        const float4* hq = (const float4*)&hist[ss][t - 1][0];
#pragma unroll
        for (int q = 0; q < 16; ++q) {
          float4 h4 = hq[q];
          ah += h4.x * whc[4 * q]     + h4.y * whc[4 * q + 1]
              + h4.z * whc[4 * q + 2] + h4.w * whc[4 * q + 3];
        }
      }
      ghl[ss][tid] = ah + bhg;
    }
    __syncthreads();
#pragma unroll
    for (int base = 0; base < 256; base += 192) {
      int tk = base + tid;
      if (tk < 256) {
        int ss = tk >> 6, i = tk & 63;
        float xr = gxl[ss][i], xz = gxl[ss][64 + i], xn = gxl[ss][128 + i];
        float hr = ghl[ss][i], hz = ghl[ss][64 + i], hn = ghl[ss][128 + i];
        float r  = sigmoidf(xr + hr);
        float z  = sigmoidf(xz + hz);
        float nn = tanh_fast(xn + r * hn);
        float hp = (t == 0) ? 0.f : hist[ss][t - 1][i];
        hist[ss][t][i] = (1.f - z) * nn + z * hp;
      }
    }
    __syncthreads();
  }
  if (tid < 20) {
    int ss = tid / 5, kk = tid % 5;
    float d = 0.f;
#pragma unroll
    for (int i = 0; i < 64; ++i) d += hist[ss][kk][i] * hist[ss][4][i];
    dls[ss][kk] = d;
  }
  __syncthreads();
  if (tid < 20) {
    int ss = tid / 5, kk = tid % 5;
    float mx = -3.4e38f;
#pragma unroll
    for (int j = 0; j < 5; ++j) mx = fmaxf(mx, dls[ss][j]);
    als[ss][kk] = __expf(dls[ss][kk] - mx);
  }
  __syncthreads();
  for (int idx = tid; idx < 256; idx += 192) {
    int ss = idx >> 6, i = idx & 63;
    float sum = 0.f, a = 0.f;
#pragma unroll
    for (int kk = 0; kk < 5; ++kk) sum += als[ss][kk];
#pragma unroll
    for (int kk = 0; kk < 5; ++kk) a += als[ss][kk] * hist[ss][kk][i];
    outv[(size_t)(s0 + ss) * 64 + i] = a / sum;
  }
}

// ---------------- kernel 5: bilinear fusion X = tanh(ct . Wb . qt + bb) ----------
__global__ __launch_bounds__(256) void k_bilinear(
    const float* __restrict__ ct, const float* __restrict__ qt,
    const float* __restrict__ Wb, const float* __restrict__ bb,
    float* __restrict__ X) {
  const int bn0 = blockIdx.x * 4;
  const int tid = threadIdx.x;
  __shared__ float ctl[4][64], qtl[4][64];
  {
    int ss = tid >> 6, i = tid & 63;
    ctl[ss][i] = ct[(size_t)(bn0 + ss) * 64 + i];
    qtl[ss][i] = qt[(size_t)(bn0 + ss) * 64 + i];
  }
  __syncthreads();
  const int o = tid >> 2, part = tid & 3, j0 = part << 4;
  float qr[4][16];
#pragma unroll
  for (int pp = 0; pp < 4; ++pp)
#pragma unroll
    for (int q = 0; q < 16; ++q) qr[pp][q] = qtl[pp][j0 + q];
  float acc[4] = {0.f, 0.f, 0.f, 0.f};
  const float* wb = Wb + (size_t)o * 4096 + j0;
  for (int i = 0; i < 64; ++i) {
    const float4* w4 = (const float4*)(wb + i * 64);
    float tmp[4] = {0.f, 0.f, 0.f, 0.f};
#pragma unroll
    for (int q = 0; q < 4; ++q) {
      float4 w = w4[q];
#pragma unroll
      for (int pp = 0; pp < 4; ++pp)
        tmp[pp] += w.x * qr[pp][4 * q]     + w.y * qr[pp][4 * q + 1]
                 + w.z * qr[pp][4 * q + 2] + w.w * qr[pp][4 * q + 3];
    }
#pragma unroll
    for (int pp = 0; pp < 4; ++pp) acc[pp] += ctl[pp][i] * tmp[pp];
  }
#pragma unroll
  for (int pp = 0; pp < 4; ++pp) {
    acc[pp] += __shfl_xor(acc[pp], 1);
    acc[pp] += __shfl_xor(acc[pp], 2);
  }
  if (part == 0) {
    float bbv = bb[o];
#pragma unroll
    for (int pp = 0; pp < 4; ++pp)
      X[(size_t)(bn0 + pp) * 64 + o] = tanh_fast(acc[pp] + bbv);
  }
}

// ---------------- kernel 6: GAT layer 1 fully fused per (b, head) ----------
__global__ __launch_bounds__(256) void k_gat1(
    const float* __restrict__ X, const float* __restrict__ W1,
    const float* __restrict__ a1, const float* __restrict__ adj,
    float* __restrict__ X2) {
  const int b = blockIdx.x >> 3, k = blockIdx.x & 7;
  const int tid = threadIdx.x;
  __shared__ __align__(16) float whd[128][68];
  __shared__ float w1l[64][64];
  __shared__ float d1l[128], d2l[128];
  for (int v = tid; v < 4096; v += 256) w1l[v >> 6][v & 63] = W1[(size_t)k * 4096 + v];
  __syncthreads();
  {
    const int f = tid & 63, ng = tid >> 6;
    const float* Xb = X + (size_t)b * 128 * 64;
    for (int n = ng * 32; n < ng * 32 + 32; ++n) {
      float a = 0.f;
#pragma unroll
      for (int h = 0; h < 64; ++h) a += Xb[n * 64 + h] * w1l[h][f];
      whd[n][f] = a;
    }
  }
  __syncthreads();
  if (tid < 128) {
    const int n = tid;
    float da = 0.f, db = 0.f;
#pragma unroll
    for (int f = 0; f < 64; ++f) {
      float w = whd[n][f];
      da += w * a1[k * 128 + f];
      db += w * a1[k * 128 + 64 + f];
    }
    d1l[n] = da; d2l[n] = db;
  }
  __syncthreads();
  {
    const int n = tid & 127, fh = tid >> 7;
    unsigned long long mlo = 0ull, mhi = 0ull;
    for (int m = 0; m < 64; ++m) if (adj[n * 128 + m] > 0.f)      mlo |= (1ull << m);
    for (int m = 0; m < 64; ++m) if (adj[n * 128 + 64 + m] > 0.f) mhi |= (1ull << m);
    const float d1n = d1l[n];
    float mx = -3.4e38f;
    for (int m = 0; m < 128; ++m) {
      bool on = (m < 64) ? (((mlo >> m) & 1ull) != 0) : (((mhi >> (m - 64)) & 1ull) != 0);
      float e = lrelu(d1n + d2l[m]);
      mx = fmaxf(mx, on ? e : -3.4e38f);
    }
    float sum = 0.f;
    float acc[32];
#pragma unroll
    for (int q = 0; q < 32; ++q) acc[q] = 0.f;
    for (int m = 0; m < 128; ++m) {
      bool on = (m < 64) ? (((mlo >> m) & 1ull) != 0) : (((mhi >> (m - 64)) & 1ull) != 0);
      float w = on ? __expf(lrelu(d1n + d2l[m]) - mx) : 0.f;
      sum += w;
      const float4* wr = (const float4*)&whd[m][fh * 32];
#pragma unroll
      for (int q8 = 0; q8 < 8; ++q8) {
        float4 wv = wr[q8];
        acc[4 * q8]     += w * wv.x;
        acc[4 * q8 + 1] += w * wv.y;
        acc[4 * q8 + 2] += w * wv.z;
        acc[4 * q8 + 3] += w * wv.w;
      }
    }
    float inv = 1.f / sum;
    float* dst = X2 + ((size_t)b * 128 + n) * 512 + k * 64 + fh * 32;
#pragma unroll
    for (int q = 0; q < 32; ++q) {
      float v = acc[q] * inv;
      dst[q] = v > 0.f ? v : (__expf(v) - 1.f);
    }
  }
}

// ---------------- kernel 7: merged head (out1, Wh2=X2@W2, GAT2 softmax, residual) ----------
__global__ __launch_bounds__(256) void k_head(
    const float* __restrict__ X, const float* __restrict__ Wx, const float* __restrict__ bx,
    const float* __restrict__ X2, const float* __restrict__ W2, const float* __restrict__ a2,
    const float* __restrict__ adj, float* __restrict__ out) {
  const int b = blockIdx.x;
  const int tid = threadIdx.x;
  __shared__ float w2l[1024];
  __shared__ float wh2l[128][2];
  __shared__ float d2aL[128], d2bL[128];
  __shared__ float out1L[128][2];
  for (int v = tid; v < 1024; v += 256) w2l[v] = W2[v];
  __syncthreads();
  const int w = tid >> 6, l = tid & 63;
  const float a20 = a2[0], a21 = a2[1], a22 = a2[2], a23 = a2[3];
  // Wh2 rows: wave w handles n = w*32 .. w*32+31, full-wave dot-512 + reduce
  for (int it = 0; it < 32; ++it) {
    int n = w * 32 + it;
    const float* xr = X2 + ((size_t)b * 128 + n) * 512 + l * 8;
    float4 xa = *(const float4*)xr;
    float4 xb = *(const float4*)(xr + 4);
    float xs[8] = {xa.x, xa.y, xa.z, xa.w, xb.x, xb.y, xb.z, xb.w};
    float s0 = 0.f, s1 = 0.f;
#pragma unroll
    for (int j = 0; j < 8; ++j) {
      s0 += xs[j] * w2l[(l * 8 + j) * 2];
      s1 += xs[j] * w2l[(l * 8 + j) * 2 + 1];
    }
#pragma unroll
    for (int d = 1; d < 64; d <<= 1) { s0 += __shfl_xor(s0, d); s1 += __shfl_xor(s1, d); }
    if (l == 0) {
      wh2l[n][0] = s0; wh2l[n][1] = s1;
      d2aL[n] = s0 * a20 + s1 * a21;
      d2bL[n] = s0 * a22 + s1 * a23;
    }
  }
  if (tid < 128) {
    int n = tid;
    const float* xrow = X + ((size_t)b * 128 + n) * 64;
#pragma unroll
    for (int c = 0; c < 2; ++c) {
      float a = 0.f;
#pragma unroll
      for (int h = 0; h < 64; ++h) a += xrow[h] * Wx[(n * 2 + c) * 64 + h];
      out1L[n][c] = tanh_fast(a + bx[n * 2 + c]);
    }
  }
  __syncthreads();
  if (tid < 128) {
    const int n = tid;
    unsigned long long mlo = 0ull, mhi = 0ull;
    for (int m = 0; m < 64; ++m) if (adj[n * 128 + m] > 0.f)      mlo |= (1ull << m);
    for (int m = 0; m < 64; ++m) if (adj[n * 128 + 64 + m] > 0.f) mhi |= (1ull << m);
    const float dan = d2aL[n];
    float mx = -3.4e38f;
    for (int m = 0; m < 128; ++m) {
      bool on = (m < 64) ? (((mlo >> m) & 1ull) != 0) : (((mhi >> (m - 64)) & 1ull) != 0);
      float e = lrelu(dan + d2bL[m]);
      mx = fmaxf(mx, on ? e : -3.4e38f);
    }
    float sum = 0.f, x0 = 0.f, x1 = 0.f;
    for (int m = 0; m < 128; ++m) {
      bool on = (m < 64) ? (((mlo >> m) & 1ull) != 0) : (((mhi >> (m - 64)) & 1ull) != 0);
      float wgt = on ? __expf(lrelu(dan + d2bL[m]) - mx) : 0.f;
      sum += wgt; x0 += wgt * wh2l[m][0]; x1 += wgt * wh2l[m][1];
    }
    float inv = 1.f / sum;
    out[(size_t)(b * 2 + 0) * 128 + n] = x0 * inv + out1L[n][0];
    out[(size_t)(b * 2 + 1) * 128 + n] = x1 * inv + out1L[n][1];
  }
}

} // namespace

extern "C" void kernel_launch(void* const* d_in, const int* in_sizes, int n_in,
                              void* d_out, int out_size, void* d_ws, size_t ws_size,
                              hipStream_t stream) {
  (void)in_sizes; (void)n_in; (void)out_size;
  const float* s      = (const float*)d_in[0];
  const float* p      = (const float*)d_in[1];
  const float* adj    = (const float*)d_in[2];
  const float* sm1_Wi = (const float*)d_in[3];
  const float* sm1_Wh = (const float*)d_in[4];
  const float* sm1_bi = (const float*)d_in[5];
  const float* sm1_bh = (const float*)d_in[6];
  const float* sm2_Wi = (const float*)d_in[7];
  const float* sm2_Wh = (const float*)d_in[8];
  const float* sm2_bi = (const float*)d_in[9];
  const float* sm2_bh = (const float*)d_in[10];
  const float* pr_Wi  = (const float*)d_in[11];
  const float* pr_Wh  = (const float*)d_in[12];
  const float* pr_bi  = (const float*)d_in[13];
  const float* pr_bh  = (const float*)d_in[14];
  const float* Wb     = (const float*)d_in[15];
  const float* bb     = (const float*)d_in[16];
  const float* Wx     = (const float*)d_in[17];
  const float* bx     = (const float*)d_in[18];
  const float* W1     = (const float*)d_in[19];
  const float* a1     = (const float*)d_in[20];
  const float* W2     = (const float*)d_in[21];
  const float* a2     = (const float*)d_in[22];

  // workspace layout (bytes); total = 43,515,904  (Bt aliases the X2 region)
  if (ws_size < 43515904u) return;
  char* ws = (char*)d_ws;
  __half* gx1 = (__half*)ws;                 // 39,321,600
  float* cv   = (float*)(ws + 39321600);     // 1,310,720
  float* ct   = (float*)(ws + 40632320);     // 262,144
  float* qt   = (float*)(ws + 40894464);     // 262,144
  float* X    = (float*)(ws + 41156608);     // 262,144
  float* X2   = (float*)(ws + 41418752);     // 2,097,152
  _Float16* Bt = (_Float16*)(ws + 41418752); // 147,456 (dead before X2 is written)

  hipLaunchKernelGGL(k_cvtB,     dim3(288),  dim3(256), 0, stream, sm1_Wi, Bt);
  hipLaunchKernelGGL(k_gx1,      dim3(800),  dim3(256), 0, stream, s, Bt, sm1_bi, gx1);
  hipLaunchKernelGGL(k_scan1,    dim3(640),  dim3(192), 0, stream, gx1, sm1_Wh, sm1_bh, cv);
  hipLaunchKernelGGL(k_scan2,    dim3(256),  dim3(192), 0, stream, cv, sm2_Wi, sm2_Wh, sm2_bi, sm2_bh, ct);
  hipLaunchKernelGGL(k_scan3,    dim3(256),  dim3(192), 0, stream, p, pr_Wi, pr_Wh, pr_bi, pr_bh, qt);
  hipLaunchKernelGGL(k_bilinear, dim3(256),  dim3(256), 0, stream, ct, qt, Wb, bb, X);
  hipLaunchKernelGGL(k_gat1,     dim3(64),   dim3(256), 0, stream, X, W1, a1, adj, X2);
  hipLaunchKernelGGL(k_head,     dim3(8),    dim3(256), 0, stream, X, Wx, bx, X2, W2, a2, adj, (float*)d_out);
}

// Round 4
// 503.329 us; speedup vs baseline: 1.4995x; 1.0994x over previous
//
#include <hip/hip_runtime.h>
#include <hip/hip_bf16.h>
#include <hip/hip_fp16.h>

#define DI __device__ __forceinline__

namespace {

constexpr int G_  = 192;    // 3*H
constexpr int FT_ = 384;

typedef _Float16 f16x8 __attribute__((ext_vector_type(8)));
typedef _Float16 f16x4 __attribute__((ext_vector_type(4)));
typedef float    f32x4 __attribute__((ext_vector_type(4)));

DI float lrelu(float x) { return x > 0.f ? x : 0.2f * x; }
DI float sigmoidf(float x) { return 1.f / (1.f + __expf(-x)); }
DI float tanh_fast(float x) { float e = __expf(2.f * x); return 1.f - 2.f / (e + 1.f); }

// ---------------- kernel 0: Bt[g][f] = fp16(Wi[f][g]) ----------
__global__ __launch_bounds__(256) void k_cvtB(
    const float* __restrict__ Wi, _Float16* __restrict__ Bt) {
  int v = blockIdx.x * 256 + threadIdx.x;   // 73728 = 192*384
  int g = v / 384, f = v % 384;
  Bt[v] = (_Float16)Wi[f * 192 + g];
}

// ---------------- kernel 1: gx1 = s_slab^T @ Wi + bi via fp16 MFMA ----------
// 1 block per slab (b,t,k). Output layout is the scan's per-lane layout:
//   gx[((k*40 + b*5 + t)*8 + ngrp)*3 + gate][lane][t'(4)][r(4)]  (fp16, 1024 per gate blk)
// where lane = seq + 16*rg, i = 16*t' + 4*rg + r, gate in {r,z,n}.
__global__ __launch_bounds__(256) void k_gx1(
    const float* __restrict__ s, const _Float16* __restrict__ Bt,
    const float* __restrict__ bi, _Float16* __restrict__ gx1) {
  const int slab = blockIdx.x;
  const int b = slab / 100, rem = slab % 100, t = rem / 20, k = rem % 20;
  const float* A = s + (size_t)((b * 5 + t) * 20 + k) * (FT_ * 128);  // [f][n]
  __shared__ __align__(16) _Float16 AsL[128 * 40];   // [n][k'] rows padded to 40 halves
  __shared__ __align__(16) _Float16 BsL[192 * 40];   // [g][k']
  __shared__ __align__(16) float bisL[192];
  const int tid = threadIdx.x;
  if (tid < 192) bisL[tid] = bi[tid];
  const int w = tid >> 6, l = tid & 63;
  const int lr = l & 15, lk = l >> 4;     // seq / rg

  f32x4 acc[12][2];
#pragma unroll
  for (int gt = 0; gt < 12; ++gt)
#pragma unroll
    for (int nt = 0; nt < 2; ++nt) acc[gt][nt] = (f32x4){0.f, 0.f, 0.f, 0.f};

  for (int kc = 0; kc < 12; ++kc) {
    const int f0 = kc * 32;
#pragma unroll
    for (int pass = 0; pass < 2; ++pass) {
      int task = tid + 256 * pass;
      int n = task & 127, oct = task >> 7;
      const float* src = A + (size_t)(f0 + oct * 8) * 128 + n;
      float v[8];
#pragma unroll
      for (int j = 0; j < 8; ++j) v[j] = src[j * 128];
      f16x8 h;
#pragma unroll
      for (int j = 0; j < 8; ++j) h[j] = (_Float16)v[j];
      *(f16x8*)&AsL[n * 40 + oct * 8] = h;
    }
#pragma unroll
    for (int pass = 0; pass < 3; ++pass) {
      int c = tid + 256 * pass;
      int g = c >> 2, oct = c & 3;
      f16x8 h = *(const f16x8*)&Bt[(size_t)g * 384 + f0 + oct * 8];
      *(f16x8*)&BsL[g * 40 + oct * 8] = h;
    }
    __syncthreads();
    f16x8 aN[2];
#pragma unroll
    for (int nt = 0; nt < 2; ++nt)
      aN[nt] = *(const f16x8*)&AsL[(w * 32 + nt * 16 + lr) * 40 + lk * 8];
#pragma unroll
    for (int gt = 0; gt < 12; ++gt) {
      f16x8 bW = *(const f16x8*)&BsL[(gt * 16 + lr) * 40 + lk * 8];
      acc[gt][0] = __builtin_amdgcn_mfma_f32_16x16x32_f16(bW, aN[0], acc[gt][0], 0, 0, 0);
      acc[gt][1] = __builtin_amdgcn_mfma_f32_16x16x32_f16(bW, aN[1], acc[gt][1], 0, 0, 0);
    }
    __syncthreads();
  }
  // epilogue: C row g = gt*16 + 4*lk + r; emit scan layout (t' = gt&3, gate = gt>>2)
  const size_t base3 = ((size_t)k * 40 + b * 5 + t) * 8;
#pragma unroll
  for (int nt = 0; nt < 2; ++nt) {
    const int ngrp = w * 2 + nt;
    _Float16* dstbase = gx1 + ((base3 + ngrp) * 3) * 1024 + (size_t)l * 16;
#pragma unroll
    for (int gate = 0; gate < 3; ++gate) {
      f16x8 h0, h1;
#pragma unroll
      for (int tq = 0; tq < 4; ++tq) {
        const int gt = gate * 4 + tq;
        f32x4 bias = *(const f32x4*)&bisL[gt * 16 + lk * 4];
        f32x4 c = acc[gt][nt];
#pragma unroll
        for (int r = 0; r < 4; ++r) {
          float v = c[r] + bias[r];
          if (tq < 2) h0[tq * 4 + r] = (_Float16)v;
          else        h1[(tq - 2) * 4 + r] = (_Float16)v;
        }
      }
      *(f16x8*)(dstbase + (size_t)gate * 1024) = h0;
      *(f16x8*)(dstbase + (size_t)gate * 1024 + 8) = h1;
    }
  }
}

// ---------------- kernel 2: SM1 GRU scan via MFMA, wave-autonomous ----------
// 320 blocks x 64 threads. Wave owns 16 sequences (b, t, ngrp), 20 steps, no barriers.
// Lane identity: seq = l&15, rg = l>>4; lane holds i = 16t' + 4rg + r (16 values).
__global__ __launch_bounds__(64, 1) void k_scan1m(
    const _Float16* __restrict__ gx, const float* __restrict__ Wh,
    const float* __restrict__ bh, float* __restrict__ cv) {
  const int wv = blockIdx.x;           // 0..319
  const int b = wv / 40, rem = wv % 40, t = rem / 8, ng = rem % 8;
  const int l = threadIdx.x;
  const int seq = l & 15, rg = l >> 4;

  __shared__ __align__(16) _Float16 histL[20][64][24];  // 48B/lane stride: full bank coverage
  __shared__ __align__(16) _Float16 red[16][72];        // [seq][i] pad->144B rows (16B-mult)

  // Wh^T A-fragments: lane holds Wh[i' = 32c + rg*8 + j][g = 16gt + seq]
  f16x8 whF[12][2];
#pragma unroll
  for (int gt = 0; gt < 12; ++gt)
#pragma unroll
    for (int c = 0; c < 2; ++c) {
      f16x8 h;
#pragma unroll
      for (int j = 0; j < 8; ++j)
        h[j] = (_Float16)Wh[(size_t)(32 * c + rg * 8 + j) * 192 + gt * 16 + seq];
      whF[gt][c] = h;
    }
  // bh in C-layout: value for (gt, r) = bh[gt*16 + rg*4 + r]
  f32x4 bhF[12];
#pragma unroll
  for (int gt = 0; gt < 12; ++gt)
    bhF[gt] = *(const f32x4*)&bh[gt * 16 + rg * 4];

  float h16[16];
#pragma unroll
  for (int j = 0; j < 16; ++j) h16[j] = 0.f;

#define GXP(kk) (gx + ((((size_t)(kk) * 40 + b * 5 + t) * 8 + ng) * 3) * 1024 + (size_t)l * 16)

  f16x8 gxc[3][2], gxn[3][2];
  {
    const _Float16* p0 = GXP(0);
    const _Float16* p1 = GXP(1);
#pragma unroll
    for (int g = 0; g < 3; ++g) {
      gxc[g][0] = *(const f16x8*)(p0 + g * 1024);
      gxc[g][1] = *(const f16x8*)(p0 + g * 1024 + 8);
      gxn[g][0] = *(const f16x8*)(p1 + g * 1024);
      gxn[g][1] = *(const f16x8*)(p1 + g * 1024 + 8);
    }
  }

  f16x8 bf0, bf1;          // h in B-fragment layout (loop-carried)
  f32x4 acc[12];

#define GATES_AND_H(KCONST_HIST)                                               \
  {                                                                            \
    _Float16* hp = &histL[KCONST_HIST][l][0];                                  \
    f16x8 p0, p1;                                                              \
    _Pragma("unroll")                                                          \
    for (int tq = 0; tq < 4; ++tq) {                                           \
      _Pragma("unroll")                                                        \
      for (int r = 0; r < 4; ++r) {                                            \
        const int idx = tq * 4 + r;                                            \
        float xr = (float)gxc[0][idx >> 3][idx & 7];                           \
        float xz = (float)gxc[1][idx >> 3][idx & 7];                           \
        float xn = (float)gxc[2][idx >> 3][idx & 7];                           \
        float hr = acc[tq][r], hz = acc[4 + tq][r], hnv = acc[8 + tq][r];      \
        float rr = sigmoidf(xr + hr);                                          \
        float zz = sigmoidf(xz + hz);                                          \
        float nn = tanh_fast(xn + rr * hnv);                                   \
        float hv = (1.f - zz) * nn + zz * h16[idx];                            \
        h16[idx] = hv;                                                         \
        if (idx < 8) p0[idx] = (_Float16)hv; else p1[idx - 8] = (_Float16)hv;  \
      }                                                                        \
    }                                                                          \
    *(f16x8*)hp = p0;                                                          \
    *(f16x8*)(hp + 8) = p1;                                                    \
  }

#define REDIST()                                                               \
  {                                                                            \
    _Pragma("unroll")                                                          \
    for (int tq = 0; tq < 4; ++tq) {                                           \
      f16x4 q;                                                                 \
      q[0] = (_Float16)h16[tq * 4 + 0]; q[1] = (_Float16)h16[tq * 4 + 1];      \
      q[2] = (_Float16)h16[tq * 4 + 2]; q[3] = (_Float16)h16[tq * 4 + 3];      \
      *(f16x4*)&red[seq][16 * tq + 4 * rg] = q;                                \
    }                                                                          \
    bf0 = *(const f16x8*)&red[seq][8 * rg];                                    \
    bf1 = *(const f16x8*)&red[seq][32 + 8 * rg];                               \
  }

  // ---- k = 0: h=0 -> gh = bh only ----
#pragma unroll
  for (int gt = 0; gt < 12; ++gt) acc[gt] = bhF[gt];
  GATES_AND_H(0)
  REDIST()

  // ---- k = 1..18 ----
  for (int k = 1; k < 19; ++k) {
#pragma unroll
    for (int g = 0; g < 3; ++g) { gxc[g][0] = gxn[g][0]; gxc[g][1] = gxn[g][1]; }
    const _Float16* pn = GXP(k + 1);
#pragma unroll
    for (int g = 0; g < 3; ++g) {
      gxn[g][0] = *(const f16x8*)(pn + g * 1024);
      gxn[g][1] = *(const f16x8*)(pn + g * 1024 + 8);
    }
#pragma unroll
    for (int gt = 0; gt < 12; ++gt) {
      acc[gt] = bhF[gt];
      acc[gt] = __builtin_amdgcn_mfma_f32_16x16x32_f16(whF[gt][0], bf0, acc[gt], 0, 0, 0);
      acc[gt] = __builtin_amdgcn_mfma_f32_16x16x32_f16(whF[gt][1], bf1, acc[gt], 0, 0, 0);
    }
    GATES_AND_H(k)
    REDIST()
  }

  // ---- k = 19 ----
#pragma unroll
  for (int g = 0; g < 3; ++g) { gxc[g][0] = gxn[g][0]; gxc[g][1] = gxn[g][1]; }
#pragma unroll
  for (int gt = 0; gt < 12; ++gt) {
    acc[gt] = bhF[gt];
    acc[gt] = __builtin_amdgcn_mfma_f32_16x16x32_f16(whF[gt][0], bf0, acc[gt], 0, 0, 0);
    acc[gt] = __builtin_amdgcn_mfma_f32_16x16x32_f16(whF[gt][1], bf1, acc[gt], 0, 0, 0);
  }
  GATES_AND_H(19)

  // ---- temporal attention (fused, wave-local) ----
  float d[20];
#pragma unroll
  for (int kk = 0; kk < 20; ++kk) {
    f16x8 a0 = *(const f16x8*)&histL[kk][l][0];
    f16x8 a1 = *(const f16x8*)&histL[kk][l][8];
    float p = 0.f;
#pragma unroll
    for (int j = 0; j < 8; ++j)
      p += (float)a0[j] * h16[j] + (float)a1[j] * h16[8 + j];
    p += __shfl_xor(p, 16);
    p += __shfl_xor(p, 32);
    d[kk] = p;
  }
  float mx = d[0];
#pragma unroll
  for (int kk = 1; kk < 20; ++kk) mx = fmaxf(mx, d[kk]);
  float sum = 0.f;
#pragma unroll
  for (int kk = 0; kk < 20; ++kk) { d[kk] = __expf(d[kk] - mx); sum += d[kk]; }
  const float inv = 1.f / sum;
  float av[16];
#pragma unroll
  for (int j = 0; j < 16; ++j) av[j] = 0.f;
#pragma unroll
  for (int kk = 0; kk < 20; ++kk) {
    f16x8 a0 = *(const f16x8*)&histL[kk][l][0];
    f16x8 a1 = *(const f16x8*)&histL[kk][l][8];
    float wgt = d[kk] * inv;
#pragma unroll
    for (int j = 0; j < 8; ++j) {
      av[j]     += wgt * (float)a0[j];
      av[8 + j] += wgt * (float)a1[j];
    }
  }
  const int n = ng * 16 + seq;
  float* dst = cv + ((size_t)(b * 128 + n) * 5 + t) * 64;
#pragma unroll
  for (int tq = 0; tq < 4; ++tq) {
    float4 o = make_float4(av[tq * 4], av[tq * 4 + 1], av[tq * 4 + 2], av[tq * 4 + 3]);
    *(float4*)&dst[16 * tq + 4 * rg] = o;
  }
#undef GXP
#undef GATES_AND_H
#undef REDIST
}

// ---------------- kernel 3: SM2 GRU (5 steps, input 64) + attention -> ct (4 seq/block) ----------
__global__ __launch_bounds__(192) void k_scan2(
    const float* __restrict__ x, const float* __restrict__ Wi,
    const float* __restrict__ Wh, const float* __restrict__ bi,
    const float* __restrict__ bh, float* __restrict__ outv) {
  const int s0 = blockIdx.x * 4;
  const int tid = threadIdx.x;
  __shared__ __align__(16) float hist[4][5][64];
  __shared__ __align__(16) float xl[4][64];
  __shared__ float ghl[4][192], gxl[4][192];
  __shared__ float dls[4][5], als[4][5];
  float wic[64], whc[64];
#pragma unroll
  for (int i = 0; i < 64; ++i) { wic[i] = Wi[i * G_ + tid]; whc[i] = Wh[i * G_ + tid]; }
  const float big = bi[tid], bhg = bh[tid];

  for (int t = 0; t < 5; ++t) {
    for (int v = tid; v < 256; v += 192) {
      int ss = v >> 6, i = v & 63;
      xl[ss][i] = x[((size_t)(s0 + ss) * 5 + t) * 64 + i];
    }
    __syncthreads();
#pragma unroll
    for (int ss = 0; ss < 4; ++ss) {
      const float4* xq = (const float4*)&xl[ss][0];
      float ax = 0.f;
#pragma unroll
      for (int q = 0; q < 16; ++q) {
        float4 v4 = xq[q];
        ax += v4.x * wic[4 * q]     + v4.y * wic[4 * q + 1]
            + v4.z * wic[4 * q + 2] + v4.w * wic[4 * q + 3];
      }
      gxl[ss][tid] = ax + big;
      float ah = 0.f;
      if (t > 0) {
        const float4* hq = (const float4*)&hist[ss][t - 1][0];
#pragma unroll
        for (int q = 0; q < 16; ++q) {
          float4 h4 = hq[q];
          ah += h4.x * whc[4 * q]     + h4.y * whc[4 * q + 1]
              + h4.z * whc[4 * q + 2] + h4.w * whc[4 * q + 3];
        }
      }
      ghl[ss][tid] = ah + bhg;
    }
    __syncthreads();
#pragma unroll
    for (int base = 0; base < 256; base += 192) {
      int tk = base + tid;
      if (tk < 256) {
        int ss = tk >> 6, i = tk & 63;
        float xr = gxl[ss][i], xz = gxl[ss][64 + i], xn = gxl[ss][128 + i];
        float hr = ghl[ss][i], hz = ghl[ss][64 + i], hn = ghl[ss][128 + i];
        float r  = sigmoidf(xr + hr);
        float z  = sigmoidf(xz + hz);
        float nn = tanh_fast(xn + r * hn);
        float hp = (t == 0) ? 0.f : hist[ss][t - 1][i];
        hist[ss][t][i] = (1.f - z) * nn + z * hp;
      }
    }
    __syncthreads();
  }
  if (tid < 20) {
    int ss = tid / 5, kk = tid % 5;
    float d = 0.f;
#pragma unroll
    for (int i = 0; i < 64; ++i) d += hist[ss][kk][i] * hist[ss][4][i];
    dls[ss][kk] = d;
  }
  __syncthreads();
  if (tid < 20) {
    int ss = tid / 5, kk = tid % 5;
    float mx = -3.4e38f;
#pragma unroll
    for (int j = 0; j < 5; ++j) mx = fmaxf(mx, dls[ss][j]);
    als[ss][kk] = __expf(dls[ss][kk] - mx);
  }
  __syncthreads();
  for (int idx = tid; idx < 256; idx += 192) {
    int ss = idx >> 6, i = idx & 63;
    float sum = 0.f, a = 0.f;
#pragma unroll
    for (int kk = 0; kk < 5; ++kk) sum += als[ss][kk];
#pragma unroll
    for (int kk = 0; kk < 5; ++kk) a += als[ss][kk] * hist[ss][kk][i];
    outv[(size_t)(s0 + ss) * 64 + i] = a / sum;
  }
}

// ---------------- kernel 4: price GRU (input dim 3) + attention -> qt (4 seq/block) ----------
__global__ __launch_bounds__(192) void k_scan3(
    const float* __restrict__ p, const float* __restrict__ Wi,
    const float* __restrict__ Wh, const float* __restrict__ bi,
    const float* __restrict__ bh, float* __restrict__ outv) {
  const int s0 = blockIdx.x * 4;
  const int tid = threadIdx.x;
  __shared__ __align__(16) float hist[4][5][64];
  __shared__ float xp[4][3];
  __shared__ float ghl[4][192], gxl[4][192];
  __shared__ float dls[4][5], als[4][5];
  float wic[3], whc[64];
#pragma unroll
  for (int f = 0; f < 3; ++f) wic[f] = Wi[f * G_ + tid];
#pragma unroll
  for (int i = 0; i < 64; ++i) whc[i] = Wh[i * G_ + tid];
  const float big = bi[tid], bhg = bh[tid];

  for (int t = 0; t < 5; ++t) {
    if (tid < 12) {
      int ss = tid / 3, f = tid % 3;
      int seq = s0 + ss, b = seq >> 7, n = seq & 127;
      xp[ss][f] = p[((size_t)(b * 5 + t) * 3 + f) * 128 + n];
    }
    __syncthreads();
#pragma unroll
    for (int ss = 0; ss < 4; ++ss) {
      gxl[ss][tid] = xp[ss][0] * wic[0] + xp[ss][1] * wic[1] + xp[ss][2] * wic[2] + big;
      float ah = 0.f;
      if (t > 0) {
        const float4* hq = (const float4*)&hist[ss][t - 1][0];
#pragma unroll
        for (int q = 0; q < 16; ++q) {
          float4 h4 = hq[q];
          ah += h4.x * whc[4 * q]     + h4.y * whc[4 * q + 1]
              + h4.z * whc[4 * q + 2] + h4.w * whc[4 * q + 3];
        }
      }
      ghl[ss][tid] = ah + bhg;
    }
    __syncthreads();
#pragma unroll
    for (int base = 0; base < 256; base += 192) {
      int tk = base + tid;
      if (tk < 256) {
        int ss = tk >> 6, i = tk & 63;
        float xr = gxl[ss][i], xz = gxl[ss][64 + i], xn = gxl[ss][128 + i];
        float hr = ghl[ss][i], hz = ghl[ss][64 + i], hn = ghl[ss][128 + i];
        float r  = sigmoidf(xr + hr);
        float z  = sigmoidf(xz + hz);
        float nn = tanh_fast(xn + r * hn);
        float hp = (t == 0) ? 0.f : hist[ss][t - 1][i];
        hist[ss][t][i] = (1.f - z) * nn + z * hp;
      }
    }
    __syncthreads();
  }
  if (tid < 20) {
    int ss = tid / 5, kk = tid % 5;
    float d = 0.f;
#pragma unroll
    for (int i = 0; i < 64; ++i) d += hist[ss][kk][i] * hist[ss][4][i];
    dls[ss][kk] = d;
  }
  __syncthreads();
  if (tid < 20) {
    int ss = tid / 5, kk = tid % 5;
    float mx = -3.4e38f;
#pragma unroll
    for (int j = 0; j < 5; ++j) mx = fmaxf(mx, dls[ss][j]);
    als[ss][kk] = __expf(dls[ss][kk] - mx);
  }
  __syncthreads();
  for (int idx = tid; idx < 256; idx += 192) {
    int ss = idx >> 6, i = idx & 63;
    float sum = 0.f, a = 0.f;
#pragma unroll
    for (int kk = 0; kk < 5; ++kk) sum += als[ss][kk];
#pragma unroll
    for (int kk = 0; kk < 5; ++kk) a += als[ss][kk] * hist[ss][kk][i];
    outv[(size_t)(s0 + ss) * 64 + i] = a / sum;
  }
}

// ---------------- kernel 5: bilinear fusion X = tanh(ct . Wb . qt + bb) ----------
__global__ __launch_bounds__(256) void k_bilinear(
    const float* __restrict__ ct, const float* __restrict__ qt,
    const float* __restrict__ Wb, const float* __restrict__ bb,
    float* __restrict__ X) {
  const int bn0 = blockIdx.x * 4;
  const int tid = threadIdx.x;
  __shared__ float ctl[4][64], qtl[4][64];
  {
    int ss = tid >> 6, i = tid & 63;
    ctl[ss][i] = ct[(size_t)(bn0 + ss) * 64 + i];
    qtl[ss][i] = qt[(size_t)(bn0 + ss) * 64 + i];
  }
  __syncthreads();
  const int o = tid >> 2, part = tid & 3, j0 = part << 4;
  float qr[4][16];
#pragma unroll
  for (int pp = 0; pp < 4; ++pp)
#pragma unroll
    for (int q = 0; q < 16; ++q) qr[pp][q] = qtl[pp][j0 + q];
  float acc[4] = {0.f, 0.f, 0.f, 0.f};
  const float* wb = Wb + (size_t)o * 4096 + j0;
  for (int i = 0; i < 64; ++i) {
    const float4* w4 = (const float4*)(wb + i * 64);
    float tmp[4] = {0.f, 0.f, 0.f, 0.f};
#pragma unroll
    for (int q = 0; q < 4; ++q) {
      float4 w = w4[q];
#pragma unroll
      for (int pp = 0; pp < 4; ++pp)
        tmp[pp] += w.x * qr[pp][4 * q]     + w.y * qr[pp][4 * q + 1]
                 + w.z * qr[pp][4 * q + 2] + w.w * qr[pp][4 * q + 3];
    }
#pragma unroll
    for (int pp = 0; pp < 4; ++pp) acc[pp] += ctl[pp][i] * tmp[pp];
  }
#pragma unroll
  for (int pp = 0; pp < 4; ++pp) {
    acc[pp] += __shfl_xor(acc[pp], 1);
    acc[pp] += __shfl_xor(acc[pp], 2);
  }
  if (part == 0) {
    float bbv = bb[o];
#pragma unroll
    for (int pp = 0; pp < 4; ++pp)
      X[(size_t)(bn0 + pp) * 64 + o] = tanh_fast(acc[pp] + bbv);
  }
}

// ---------------- kernel 6: GAT layer 1 fully fused per (b, head) ----------
__global__ __launch_bounds__(256) void k_gat1(
    const float* __restrict__ X, const float* __restrict__ W1,
    const float* __restrict__ a1, const float* __restrict__ adj,
    float* __restrict__ X2) {
  const int b = blockIdx.x >> 3, k = blockIdx.x & 7;
  const int tid = threadIdx.x;
  __shared__ __align__(16) float whd[128][68];
  __shared__ float w1l[64][64];
  __shared__ float d1l[128], d2l[128];
  for (int v = tid; v < 4096; v += 256) w1l[v >> 6][v & 63] = W1[(size_t)k * 4096 + v];
  __syncthreads();
  {
    const int f = tid & 63, ng = tid >> 6;
    const float* Xb = X + (size_t)b * 128 * 64;
    for (int n = ng * 32; n < ng * 32 + 32; ++n) {
      float a = 0.f;
#pragma unroll
      for (int h = 0; h < 64; ++h) a += Xb[n * 64 + h] * w1l[h][f];
      whd[n][f] = a;
    }
  }
  __syncthreads();
  if (tid < 128) {
    const int n = tid;
    float da = 0.f, db = 0.f;
#pragma unroll
    for (int f = 0; f < 64; ++f) {
      float w = whd[n][f];
      da += w * a1[k * 128 + f];
      db += w * a1[k * 128 + 64 + f];
    }
    d1l[n] = da; d2l[n] = db;
  }
  __syncthreads();
  {
    const int n = tid & 127, fh = tid >> 7;
    unsigned long long mlo = 0ull, mhi = 0ull;
    for (int m = 0; m < 64; ++m) if (adj[n * 128 + m] > 0.f)      mlo |= (1ull << m);
    for (int m = 0; m < 64; ++m) if (adj[n * 128 + 64 + m] > 0.f) mhi |= (1ull << m);
    const float d1n = d1l[n];
    float mx = -3.4e38f;
    for (int m = 0; m < 128; ++m) {
      bool on = (m < 64) ? (((mlo >> m) & 1ull) != 0) : (((mhi >> (m - 64)) & 1ull) != 0);
      float e = lrelu(d1n + d2l[m]);
      mx = fmaxf(mx, on ? e : -3.4e38f);
    }
    float sum = 0.f;
    float acc[32];
#pragma unroll
    for (int q = 0; q < 32; ++q) acc[q] = 0.f;
    for (int m = 0; m < 128; ++m) {
      bool on = (m < 64) ? (((mlo >> m) & 1ull) != 0) : (((mhi >> (m - 64)) & 1ull) != 0);
      float w = on ? __expf(lrelu(d1n + d2l[m]) - mx) : 0.f;
      sum += w;
      const float4* wr = (const float4*)&whd[m][fh * 32];
#pragma unroll
      for (int q8 = 0; q8 < 8; ++q8) {
        float4 wv = wr[q8];
        acc[4 * q8]     += w * wv.x;
        acc[4 * q8 + 1] += w * wv.y;
        acc[4 * q8 + 2] += w * wv.z;
        acc[4 * q8 + 3] += w * wv.w;
      }
    }
    float inv = 1.f / sum;
    float* dst = X2 + ((size_t)b * 128 + n) * 512 + k * 64 + fh * 32;
#pragma unroll
    for (int q = 0; q < 32; ++q) {
      float v = acc[q] * inv;
      dst[q] = v > 0.f ? v : (__expf(v) - 1.f);
    }
  }
}

// ---------------- kernel 7: merged head (out1, Wh2=X2@W2, GAT2 softmax, residual) ----------
__global__ __launch_bounds__(256) void k_head(
    const float* __restrict__ X, const float* __restrict__ Wx, const float* __restrict__ bx,
    const float* __restrict__ X2, const float* __restrict__ W2, const float* __restrict__ a2,
    const float* __restrict__ adj, float* __restrict__ out) {
  const int b = blockIdx.x;
  const int tid = threadIdx.x;
  __shared__ float w2l[1024];
  __shared__ float wh2l[128][2];
  __shared__ float d2aL[128], d2bL[128];
  __shared__ float out1L[128][2];
  for (int v = tid; v < 1024; v += 256) w2l[v] = W2[v];
  __syncthreads();
  const int w = tid >> 6, l = tid & 63;
  const float a20 = a2[0], a21 = a2[1], a22 = a2[2], a23 = a2[3];
  for (int it = 0; it < 32; ++it) {
    int n = w * 32 + it;
    const float* xr = X2 + ((size_t)b * 128 + n) * 512 + l * 8;
    float4 xa = *(const float4*)xr;
    float4 xb = *(const float4*)(xr + 4);
    float xs[8] = {xa.x, xa.y, xa.z, xa.w, xb.x, xb.y, xb.z, xb.w};
    float s0 = 0.f, s1 = 0.f;
#pragma unroll
    for (int j = 0; j < 8; ++j) {
      s0 += xs[j] * w2l[(l * 8 + j) * 2];
      s1 += xs[j] * w2l[(l * 8 + j) * 2 + 1];
    }
#pragma unroll
    for (int d = 1; d < 64; d <<= 1) { s0 += __shfl_xor(s0, d); s1 += __shfl_xor(s1, d); }
    if (l == 0) {
      wh2l[n][0] = s0; wh2l[n][1] = s1;
      d2aL[n] = s0 * a20 + s1 * a21;
      d2bL[n] = s0 * a22 + s1 * a23;
    }
  }
  if (tid < 128) {
    int n = tid;
    const float* xrow = X + ((size_t)b * 128 + n) * 64;
#pragma unroll
    for (int c = 0; c < 2; ++c) {
      float a = 0.f;
#pragma unroll
      for (int h = 0; h < 64; ++h) a += xrow[h] * Wx[(n * 2 + c) * 64 + h];
      out1L[n][c] = tanh_fast(a + bx[n * 2 + c]);
    }
  }
  __syncthreads();
  if (tid < 128) {
    const int n = tid;
    unsigned long long mlo = 0ull, mhi = 0ull;
    for (int m = 0; m < 64; ++m) if (adj[n * 128 + m] > 0.f)      mlo |= (1ull << m);
    for (int m = 0; m < 64; ++m) if (adj[n * 128 + 64 + m] > 0.f) mhi |= (1ull << m);
    const float dan = d2aL[n];
    float mx = -3.4e38f;
    for (int m = 0; m < 128; ++m) {
      bool on = (m < 64) ? (((mlo >> m) & 1ull) != 0) : (((mhi >> (m - 64)) & 1ull) != 0);
      float e = lrelu(dan + d2bL[m]);
      mx = fmaxf(mx, on ? e : -3.4e38f);
    }
    float sum = 0.f, x0 = 0.f, x1 = 0.f;
    for (int m = 0; m < 128; ++m) {
      bool on = (m < 64) ? (((mlo >> m) & 1ull) != 0) : (((mhi >> (m - 64)) & 1ull) != 0);
      float wgt = on ? __expf(lrelu(dan + d2bL[m]) - mx) : 0.f;
      sum += wgt; x0 += wgt * wh2l[m][0]; x1 += wgt * wh2l[m][1];
    }
    float inv = 1.f / sum;
    out[(size_t)(b * 2 + 0) * 128 + n] = x0 * inv + out1L[n][0];
    out[(size_t)(b * 2 + 1) * 128 + n] = x1 * inv + out1L[n][1];
  }
}

} // namespace

extern "C" void kernel_launch(void* const* d_in, const int* in_sizes, int n_in,
                              void* d_out, int out_size, void* d_ws, size_t ws_size,
                              hipStream_t stream) {
  (void)in_sizes; (void)n_in; (void)out_size;
  const float* s      = (const float*)d_in[0];
  const float* p      = (const float*)d_in[1];
  const float* adj    = (const float*)d_in[2];
  const float* sm1_Wi = (const float*)d_in[3];
  const float* sm1_Wh = (const float*)d_in[4];
  const float* sm1_bi = (const float*)d_in[5];
  const float* sm1_bh = (const float*)d_in[6];
  const float* sm2_Wi = (const float*)d_in[7];
  const float* sm2_Wh = (const float*)d_in[8];
  const float* sm2_bi = (const float*)d_in[9];
  const float* sm2_bh = (const float*)d_in[10];
  const float* pr_Wi  = (const float*)d_in[11];
  const float* pr_Wh  = (const float*)d_in[12];
  const float* pr_bi  = (const float*)d_in[13];
  const float* pr_bh  = (const float*)d_in[14];
  const float* Wb     = (const float*)d_in[15];
  const float* bb     = (const float*)d_in[16];
  const float* Wx     = (const float*)d_in[17];
  const float* bx     = (const float*)d_in[18];
  const float* W1     = (const float*)d_in[19];
  const float* a1     = (const float*)d_in[20];
  const float* W2     = (const float*)d_in[21];
  const float* a2     = (const float*)d_in[22];

  // workspace layout (bytes); total = 43,515,904  (Bt aliases the X2 region)
  if (ws_size < 43515904u) return;
  char* ws = (char*)d_ws;
  _Float16* gx1 = (_Float16*)ws;             // 39,321,600 (scan-layout fp16)
  float* cv   = (float*)(ws + 39321600);     // 1,310,720
  float* ct   = (float*)(ws + 40632320);     // 262,144
  float* qt   = (float*)(ws + 40894464);     // 262,144
  float* X    = (float*)(ws + 41156608);     // 262,144
  float* X2   = (float*)(ws + 41418752);     // 2,097,152
  _Float16* Bt = (_Float16*)(ws + 41418752); // 147,456 (dead before X2 is written)

  hipLaunchKernelGGL(k_cvtB,     dim3(288),  dim3(256), 0, stream, sm1_Wi, Bt);
  hipLaunchKernelGGL(k_gx1,      dim3(800),  dim3(256), 0, stream, s, Bt, sm1_bi, gx1);
  hipLaunchKernelGGL(k_scan1m,   dim3(320),  dim3(64),  0, stream, gx1, sm1_Wh, sm1_bh, cv);
  hipLaunchKernelGGL(k_scan2,    dim3(256),  dim3(192), 0, stream, cv, sm2_Wi, sm2_Wh, sm2_bi, sm2_bh, ct);
  hipLaunchKernelGGL(k_scan3,    dim3(256),  dim3(192), 0, stream, p, pr_Wi, pr_Wh, pr_bi, pr_bh, qt);
  hipLaunchKernelGGL(k_bilinear, dim3(256),  dim3(256), 0, stream, ct, qt, Wb, bb, X);
  hipLaunchKernelGGL(k_gat1,     dim3(64),   dim3(256), 0, stream, X, W1, a1, adj, X2);
  hipLaunchKernelGGL(k_head,     dim3(8),    dim3(256), 0, stream, X, Wx, bx, X2, W2, a2, adj, (float*)d_out);
}

// Round 5
// 476.484 us; speedup vs baseline: 1.5840x; 1.0563x over previous
//
#include <hip/hip_runtime.h>
#include <hip/hip_bf16.h>
#include <hip/hip_fp16.h>

#define DI __device__ __forceinline__

namespace {

constexpr int G_  = 192;    // 3*H
constexpr int FT_ = 384;

typedef _Float16 f16x8 __attribute__((ext_vector_type(8)));
typedef _Float16 f16x4 __attribute__((ext_vector_type(4)));
typedef float    f32x4 __attribute__((ext_vector_type(4)));

DI float rcpf(float x) { return __builtin_amdgcn_rcpf(x); }
DI float lrelu(float x) { return x > 0.f ? x : 0.2f * x; }
DI float sigmoidf(float x) { return rcpf(1.f + __expf(-x)); }
DI float tanh_fast(float x) { return 1.f - 2.f * rcpf(__expf(2.f * x) + 1.f); }

// ---------------- kernel 0: Bt[g][f] = fp16(Wi[f][g]) ----------
__global__ __launch_bounds__(256) void k_cvtB(
    const float* __restrict__ Wi, _Float16* __restrict__ Bt) {
  int v = blockIdx.x * 256 + threadIdx.x;   // 73728 = 192*384
  int g = v / 384, f = v % 384;
  Bt[v] = (_Float16)Wi[f * 192 + g];
}

// ---------------- kernel 1: gx1 = s_slab^T @ Wi + bi via fp16 MFMA ----------
// 1 block per slab (b,t,k). Output layout is the scan's per-lane layout:
//   gx[((k*40 + b*5 + t)*8 + ngrp)*3 + gate][lane][t'(4)][r(4)]  (fp16, 1024 per gate blk)
__global__ __launch_bounds__(256) void k_gx1(
    const float* __restrict__ s, const _Float16* __restrict__ Bt,
    const float* __restrict__ bi, _Float16* __restrict__ gx1) {
  const int slab = blockIdx.x;
  const int b = slab / 100, rem = slab % 100, t = rem / 20, k = rem % 20;
  const float* A = s + (size_t)((b * 5 + t) * 20 + k) * (FT_ * 128);  // [f][n]
  __shared__ __align__(16) _Float16 AsL[128 * 40];
  __shared__ __align__(16) _Float16 BsL[192 * 40];
  __shared__ __align__(16) float bisL[192];
  const int tid = threadIdx.x;
  if (tid < 192) bisL[tid] = bi[tid];
  const int w = tid >> 6, l = tid & 63;
  const int lr = l & 15, lk = l >> 4;

  f32x4 acc[12][2];
#pragma unroll
  for (int gt = 0; gt < 12; ++gt)
#pragma unroll
    for (int nt = 0; nt < 2; ++nt) acc[gt][nt] = (f32x4){0.f, 0.f, 0.f, 0.f};

  for (int kc = 0; kc < 12; ++kc) {
    const int f0 = kc * 32;
#pragma unroll
    for (int pass = 0; pass < 2; ++pass) {
      int task = tid + 256 * pass;
      int n = task & 127, oct = task >> 7;
      const float* src = A + (size_t)(f0 + oct * 8) * 128 + n;
      float v[8];
#pragma unroll
      for (int j = 0; j < 8; ++j) v[j] = src[j * 128];
      f16x8 h;
#pragma unroll
      for (int j = 0; j < 8; ++j) h[j] = (_Float16)v[j];
      *(f16x8*)&AsL[n * 40 + oct * 8] = h;
    }
#pragma unroll
    for (int pass = 0; pass < 3; ++pass) {
      int c = tid + 256 * pass;
      int g = c >> 2, oct = c & 3;
      f16x8 h = *(const f16x8*)&Bt[(size_t)g * 384 + f0 + oct * 8];
      *(f16x8*)&BsL[g * 40 + oct * 8] = h;
    }
    __syncthreads();
    f16x8 aN[2];
#pragma unroll
    for (int nt = 0; nt < 2; ++nt)
      aN[nt] = *(const f16x8*)&AsL[(w * 32 + nt * 16 + lr) * 40 + lk * 8];
#pragma unroll
    for (int gt = 0; gt < 12; ++gt) {
      f16x8 bW = *(const f16x8*)&BsL[(gt * 16 + lr) * 40 + lk * 8];
      acc[gt][0] = __builtin_amdgcn_mfma_f32_16x16x32_f16(bW, aN[0], acc[gt][0], 0, 0, 0);
      acc[gt][1] = __builtin_amdgcn_mfma_f32_16x16x32_f16(bW, aN[1], acc[gt][1], 0, 0, 0);
    }
    __syncthreads();
  }
  const size_t base3 = ((size_t)k * 40 + b * 5 + t) * 8;
#pragma unroll
  for (int nt = 0; nt < 2; ++nt) {
    const int ngrp = w * 2 + nt;
    _Float16* dstbase = gx1 + ((base3 + ngrp) * 3) * 1024 + (size_t)l * 16;
#pragma unroll
    for (int gate = 0; gate < 3; ++gate) {
      f16x8 h0, h1;
#pragma unroll
      for (int tq = 0; tq < 4; ++tq) {
        const int gt = gate * 4 + tq;
        f32x4 bias = *(const f32x4*)&bisL[gt * 16 + lk * 4];
        f32x4 c = acc[gt][nt];
#pragma unroll
        for (int r = 0; r < 4; ++r) {
          float v = c[r] + bias[r];
          if (tq < 2) h0[tq * 4 + r] = (_Float16)v;
          else        h1[(tq - 2) * 4 + r] = (_Float16)v;
        }
      }
      *(f16x8*)(dstbase + (size_t)gate * 1024) = h0;
      *(f16x8*)(dstbase + (size_t)gate * 1024 + 8) = h1;
    }
  }
}

// ---------------- kernel 2: SM1 GRU scan via MFMA, wave-autonomous ----------
// 320 blocks x 64 threads. Wave owns 16 sequences; 20 steps; no barriers.
// Outputs cv as fp16 [seq][t][64] (B-fragment-ready for scan2m).
__global__ __launch_bounds__(64, 1) void k_scan1m(
    const _Float16* __restrict__ gx, const float* __restrict__ Wh,
    const float* __restrict__ bh, _Float16* __restrict__ cvh) {
  const int wv = blockIdx.x;           // 0..319
  const int b = wv / 40, rem = wv % 40, t = rem / 8, ng = rem % 8;
  const int l = threadIdx.x;
  const int seq = l & 15, rg = l >> 4;

  __shared__ __align__(16) _Float16 histL[20][64][24];
  __shared__ __align__(16) _Float16 red[16][72];

  f16x8 whF[12][2];
#pragma unroll
  for (int gt = 0; gt < 12; ++gt)
#pragma unroll
    for (int c = 0; c < 2; ++c) {
      f16x8 h;
#pragma unroll
      for (int j = 0; j < 8; ++j)
        h[j] = (_Float16)Wh[(size_t)(32 * c + rg * 8 + j) * 192 + gt * 16 + seq];
      whF[gt][c] = h;
    }
  f32x4 bhF[12];
#pragma unroll
  for (int gt = 0; gt < 12; ++gt)
    bhF[gt] = *(const f32x4*)&bh[gt * 16 + rg * 4];

  float h16[16];
#pragma unroll
  for (int j = 0; j < 16; ++j) h16[j] = 0.f;

#define GXP(kk) (gx + ((((size_t)(kk) * 40 + b * 5 + t) * 8 + ng) * 3) * 1024 + (size_t)l * 16)

  f16x8 gxc[3][2], gxn[3][2], gxn2[3][2];
  {
    const _Float16* p0 = GXP(0);
    const _Float16* p1 = GXP(1);
    const _Float16* p2 = GXP(2);
#pragma unroll
    for (int g = 0; g < 3; ++g) {
      gxc[g][0]  = *(const f16x8*)(p0 + g * 1024);
      gxc[g][1]  = *(const f16x8*)(p0 + g * 1024 + 8);
      gxn[g][0]  = *(const f16x8*)(p1 + g * 1024);
      gxn[g][1]  = *(const f16x8*)(p1 + g * 1024 + 8);
      gxn2[g][0] = *(const f16x8*)(p2 + g * 1024);
      gxn2[g][1] = *(const f16x8*)(p2 + g * 1024 + 8);
    }
  }

  f16x8 bf0, bf1;
  f32x4 acc[12];

#define GATES_AND_H(KCONST_HIST)                                               \
  {                                                                            \
    _Float16* hp = &histL[KCONST_HIST][l][0];                                  \
    f16x8 p0, p1;                                                              \
    _Pragma("unroll")                                                          \
    for (int tq = 0; tq < 4; ++tq) {                                           \
      _Pragma("unroll")                                                        \
      for (int r = 0; r < 4; ++r) {                                            \
        const int idx = tq * 4 + r;                                            \
        float xr = (float)gxc[0][idx >> 3][idx & 7];                           \
        float xz = (float)gxc[1][idx >> 3][idx & 7];                           \
        float xn = (float)gxc[2][idx >> 3][idx & 7];                           \
        float hr = acc[tq][r], hz = acc[4 + tq][r], hnv = acc[8 + tq][r];      \
        float rr = sigmoidf(xr + hr);                                          \
        float zz = sigmoidf(xz + hz);                                          \
        float nn = tanh_fast(xn + rr * hnv);                                   \
        float hv = (1.f - zz) * nn + zz * h16[idx];                            \
        h16[idx] = hv;                                                         \
        if (idx < 8) p0[idx] = (_Float16)hv; else p1[idx - 8] = (_Float16)hv;  \
      }                                                                        \
    }                                                                          \
    *(f16x8*)hp = p0;                                                          \
    *(f16x8*)(hp + 8) = p1;                                                    \
  }

#define REDIST()                                                               \
  {                                                                            \
    _Pragma("unroll")                                                          \
    for (int tq = 0; tq < 4; ++tq) {                                           \
      f16x4 q;                                                                 \
      q[0] = (_Float16)h16[tq * 4 + 0]; q[1] = (_Float16)h16[tq * 4 + 1];      \
      q[2] = (_Float16)h16[tq * 4 + 2]; q[3] = (_Float16)h16[tq * 4 + 3];      \
      *(f16x4*)&red[seq][16 * tq + 4 * rg] = q;                                \
    }                                                                          \
    bf0 = *(const f16x8*)&red[seq][8 * rg];                                    \
    bf1 = *(const f16x8*)&red[seq][32 + 8 * rg];                               \
  }

  // ---- k = 0 ----
#pragma unroll
  for (int gt = 0; gt < 12; ++gt) acc[gt] = bhF[gt];
  GATES_AND_H(0)
  REDIST()

  // ---- k = 1..18 (prefetch depth 2) ----
  for (int k = 1; k < 19; ++k) {
#pragma unroll
    for (int g = 0; g < 3; ++g) {
      gxc[g][0] = gxn[g][0];  gxc[g][1] = gxn[g][1];
      gxn[g][0] = gxn2[g][0]; gxn[g][1] = gxn2[g][1];
    }
    if (k < 18) {
      const _Float16* pn = GXP(k + 2);
#pragma unroll
      for (int g = 0; g < 3; ++g) {
        gxn2[g][0] = *(const f16x8*)(pn + g * 1024);
        gxn2[g][1] = *(const f16x8*)(pn + g * 1024 + 8);
      }
    }
#pragma unroll
    for (int gt = 0; gt < 12; ++gt) {
      acc[gt] = bhF[gt];
      acc[gt] = __builtin_amdgcn_mfma_f32_16x16x32_f16(whF[gt][0], bf0, acc[gt], 0, 0, 0);
      acc[gt] = __builtin_amdgcn_mfma_f32_16x16x32_f16(whF[gt][1], bf1, acc[gt], 0, 0, 0);
    }
    GATES_AND_H(k)
    REDIST()
  }

  // ---- k = 19 ----
#pragma unroll
  for (int g = 0; g < 3; ++g) { gxc[g][0] = gxn[g][0]; gxc[g][1] = gxn[g][1]; }
#pragma unroll
  for (int gt = 0; gt < 12; ++gt) {
    acc[gt] = bhF[gt];
    acc[gt] = __builtin_amdgcn_mfma_f32_16x16x32_f16(whF[gt][0], bf0, acc[gt], 0, 0, 0);
    acc[gt] = __builtin_amdgcn_mfma_f32_16x16x32_f16(whF[gt][1], bf1, acc[gt], 0, 0, 0);
  }
  GATES_AND_H(19)

  // ---- temporal attention ----
  float d[20];
#pragma unroll
  for (int kk = 0; kk < 20; ++kk) {
    f16x8 a0 = *(const f16x8*)&histL[kk][l][0];
    f16x8 a1 = *(const f16x8*)&histL[kk][l][8];
    float p = 0.f;
#pragma unroll
    for (int j = 0; j < 8; ++j)
      p += (float)a0[j] * h16[j] + (float)a1[j] * h16[8 + j];
    p += __shfl_xor(p, 16);
    p += __shfl_xor(p, 32);
    d[kk] = p;
  }
  float mx = d[0];
#pragma unroll
  for (int kk = 1; kk < 20; ++kk) mx = fmaxf(mx, d[kk]);
  float sum = 0.f;
#pragma unroll
  for (int kk = 0; kk < 20; ++kk) { d[kk] = __expf(d[kk] - mx); sum += d[kk]; }
  const float inv = rcpf(sum);
  float av[16];
#pragma unroll
  for (int j = 0; j < 16; ++j) av[j] = 0.f;
#pragma unroll
  for (int kk = 0; kk < 20; ++kk) {
    f16x8 a0 = *(const f16x8*)&histL[kk][l][0];
    f16x8 a1 = *(const f16x8*)&histL[kk][l][8];
    float wgt = d[kk] * inv;
#pragma unroll
    for (int j = 0; j < 8; ++j) {
      av[j]     += wgt * (float)a0[j];
      av[8 + j] += wgt * (float)a1[j];
    }
  }
  const int n = ng * 16 + seq;
  const size_t seqg = (size_t)b * 128 + n;
  _Float16* dst = cvh + (seqg * 5 + t) * 64;
#pragma unroll
  for (int tq = 0; tq < 4; ++tq) {
    f16x4 q;
    q[0] = (_Float16)av[tq * 4 + 0]; q[1] = (_Float16)av[tq * 4 + 1];
    q[2] = (_Float16)av[tq * 4 + 2]; q[3] = (_Float16)av[tq * 4 + 3];
    *(f16x4*)&dst[16 * tq + 4 * rg] = q;
  }
#undef GXP
#undef GATES_AND_H
#undef REDIST
}

// ---------------- kernel 3: SM2 GRU scan via MFMA (5 steps) -> ct fp32 ----------
// 64 blocks x 64 threads; wave owns 16 sequences; input projection also MFMA.
__global__ __launch_bounds__(64, 1) void k_scan2m(
    const _Float16* __restrict__ cvh, const float* __restrict__ Wi,
    const float* __restrict__ Wh, const float* __restrict__ bi,
    const float* __restrict__ bh, float* __restrict__ ct) {
  const int l = threadIdx.x;
  const int seq = l & 15, rg = l >> 4;
  const size_t seqg0 = (size_t)blockIdx.x * 16;

  __shared__ __align__(16) _Float16 histL[5][64][24];
  __shared__ __align__(16) _Float16 red[16][72];

  f16x8 wiF[12][2], whF[12][2];
#pragma unroll
  for (int gt = 0; gt < 12; ++gt)
#pragma unroll
    for (int c = 0; c < 2; ++c) {
      f16x8 hi, hh;
#pragma unroll
      for (int j = 0; j < 8; ++j) {
        hi[j] = (_Float16)Wi[(size_t)(32 * c + rg * 8 + j) * 192 + gt * 16 + seq];
        hh[j] = (_Float16)Wh[(size_t)(32 * c + rg * 8 + j) * 192 + gt * 16 + seq];
      }
      wiF[gt][c] = hi; whF[gt][c] = hh;
    }
  f32x4 biF[12], bhF[12];
#pragma unroll
  for (int gt = 0; gt < 12; ++gt) {
    biF[gt] = *(const f32x4*)&bi[gt * 16 + rg * 4];
    bhF[gt] = *(const f32x4*)&bh[gt * 16 + rg * 4];
  }

  float h16[16];
#pragma unroll
  for (int j = 0; j < 16; ++j) h16[j] = 0.f;
  f16x8 bf0, bf1;

#pragma unroll
  for (int t = 0; t < 5; ++t) {
    const _Float16* xp = cvh + ((seqg0 + seq) * 5 + t) * 64;
    f16x8 xf0 = *(const f16x8*)(xp + 8 * rg);
    f16x8 xf1 = *(const f16x8*)(xp + 32 + 8 * rg);
    f32x4 accX[12], accH[12];
#pragma unroll
    for (int gt = 0; gt < 12; ++gt) {
      accX[gt] = biF[gt];
      accX[gt] = __builtin_amdgcn_mfma_f32_16x16x32_f16(wiF[gt][0], xf0, accX[gt], 0, 0, 0);
      accX[gt] = __builtin_amdgcn_mfma_f32_16x16x32_f16(wiF[gt][1], xf1, accX[gt], 0, 0, 0);
      accH[gt] = bhF[gt];
      if (t > 0) {
        accH[gt] = __builtin_amdgcn_mfma_f32_16x16x32_f16(whF[gt][0], bf0, accH[gt], 0, 0, 0);
        accH[gt] = __builtin_amdgcn_mfma_f32_16x16x32_f16(whF[gt][1], bf1, accH[gt], 0, 0, 0);
      }
    }
    _Float16* hp = &histL[t][l][0];
    f16x8 p0, p1;
#pragma unroll
    for (int tq = 0; tq < 4; ++tq) {
#pragma unroll
      for (int r = 0; r < 4; ++r) {
        const int idx = tq * 4 + r;
        float xr = accX[tq][r], xz = accX[4 + tq][r], xn = accX[8 + tq][r];
        float hr = accH[tq][r], hz = accH[4 + tq][r], hnv = accH[8 + tq][r];
        float rr = sigmoidf(xr + hr);
        float zz = sigmoidf(xz + hz);
        float nn = tanh_fast(xn + rr * hnv);
        float hv = (1.f - zz) * nn + zz * h16[idx];
        h16[idx] = hv;
        if (idx < 8) p0[idx] = (_Float16)hv; else p1[idx - 8] = (_Float16)hv;
      }
    }
    *(f16x8*)hp = p0;
    *(f16x8*)(hp + 8) = p1;
    if (t < 4) {
#pragma unroll
      for (int tq = 0; tq < 4; ++tq) {
        f16x4 q;
        q[0] = (_Float16)h16[tq * 4 + 0]; q[1] = (_Float16)h16[tq * 4 + 1];
        q[2] = (_Float16)h16[tq * 4 + 2]; q[3] = (_Float16)h16[tq * 4 + 3];
        *(f16x4*)&red[seq][16 * tq + 4 * rg] = q;
      }
      bf0 = *(const f16x8*)&red[seq][8 * rg];
      bf1 = *(const f16x8*)&red[seq][32 + 8 * rg];
    }
  }

  // attention over 5 steps
  float d[5];
#pragma unroll
  for (int kk = 0; kk < 5; ++kk) {
    f16x8 a0 = *(const f16x8*)&histL[kk][l][0];
    f16x8 a1 = *(const f16x8*)&histL[kk][l][8];
    float p = 0.f;
#pragma unroll
    for (int j = 0; j < 8; ++j)
      p += (float)a0[j] * h16[j] + (float)a1[j] * h16[8 + j];
    p += __shfl_xor(p, 16);
    p += __shfl_xor(p, 32);
    d[kk] = p;
  }
  float mx = d[0];
#pragma unroll
  for (int kk = 1; kk < 5; ++kk) mx = fmaxf(mx, d[kk]);
  float sum = 0.f;
#pragma unroll
  for (int kk = 0; kk < 5; ++kk) { d[kk] = __expf(d[kk] - mx); sum += d[kk]; }
  const float inv = rcpf(sum);
  float av[16];
#pragma unroll
  for (int j = 0; j < 16; ++j) av[j] = 0.f;
#pragma unroll
  for (int kk = 0; kk < 5; ++kk) {
    f16x8 a0 = *(const f16x8*)&histL[kk][l][0];
    f16x8 a1 = *(const f16x8*)&histL[kk][l][8];
    float wgt = d[kk] * inv;
#pragma unroll
    for (int j = 0; j < 8; ++j) {
      av[j]     += wgt * (float)a0[j];
      av[8 + j] += wgt * (float)a1[j];
    }
  }
  float* dst = ct + (seqg0 + seq) * 64;
#pragma unroll
  for (int tq = 0; tq < 4; ++tq) {
    float4 o = make_float4(av[tq * 4], av[tq * 4 + 1], av[tq * 4 + 2], av[tq * 4 + 3]);
    *(float4*)&dst[16 * tq + 4 * rg] = o;
  }
}

// ---------------- kernel 4: price GRU (input dim 3) + attention -> qt (4 seq/block) ----------
__global__ __launch_bounds__(192) void k_scan3(
    const float* __restrict__ p, const float* __restrict__ Wi,
    const float* __restrict__ Wh, const float* __restrict__ bi,
    const float* __restrict__ bh, float* __restrict__ outv) {
  const int s0 = blockIdx.x * 4;
  const int tid = threadIdx.x;
  __shared__ __align__(16) float hist[4][5][64];
  __shared__ float xp[4][3];
  __shared__ float ghl[4][192], gxl[4][192];
  __shared__ float dls[4][5], als[4][5];
  float wic[3], whc[64];
#pragma unroll
  for (int f = 0; f < 3; ++f) wic[f] = Wi[f * G_ + tid];
#pragma unroll
  for (int i = 0; i < 64; ++i) whc[i] = Wh[i * G_ + tid];
  const float big = bi[tid], bhg = bh[tid];

  for (int t = 0; t < 5; ++t) {
    if (tid < 12) {
      int ss = tid / 3, f = tid % 3;
      int seq = s0 + ss, b = seq >> 7, n = seq & 127;
      xp[ss][f] = p[((size_t)(b * 5 + t) * 3 + f) * 128 + n];
    }
    __syncthreads();
#pragma unroll
    for (int ss = 0; ss < 4; ++ss) {
      gxl[ss][tid] = xp[ss][0] * wic[0] + xp[ss][1] * wic[1] + xp[ss][2] * wic[2] + big;
      float ah = 0.f;
      if (t > 0) {
        const float4* hq = (const float4*)&hist[ss][t - 1][0];
#pragma unroll
        for (int q = 0; q < 16; ++q) {
          float4 h4 = hq[q];
          ah += h4.x * whc[4 * q]     + h4.y * whc[4 * q + 1]
              + h4.z * whc[4 * q + 2] + h4.w * whc[4 * q + 3];
        }
      }
      ghl[ss][tid] = ah + bhg;
    }
    __syncthreads();
#pragma unroll
    for (int base = 0; base < 256; base += 192) {
      int tk = base + tid;
      if (tk < 256) {
        int ss = tk >> 6, i = tk & 63;
        float xr = gxl[ss][i], xz = gxl[ss][64 + i], xn = gxl[ss][128 + i];
        float hr = ghl[ss][i], hz = ghl[ss][64 + i], hn = ghl[ss][128 + i];
        float r  = sigmoidf(xr + hr);
        float z  = sigmoidf(xz + hz);
        float nn = tanh_fast(xn + r * hn);
        float hp = (t == 0) ? 0.f : hist[ss][t - 1][i];
        hist[ss][t][i] = (1.f - z) * nn + z * hp;
      }
    }
    __syncthreads();
  }
  if (tid < 20) {
    int ss = tid / 5, kk = tid % 5;
    float d = 0.f;
#pragma unroll
    for (int i = 0; i < 64; ++i) d += hist[ss][kk][i] * hist[ss][4][i];
    dls[ss][kk] = d;
  }
  __syncthreads();
  if (tid < 20) {
    int ss = tid / 5, kk = tid % 5;
    float mx = -3.4e38f;
#pragma unroll
    for (int j = 0; j < 5; ++j) mx = fmaxf(mx, dls[ss][j]);
    als[ss][kk] = __expf(dls[ss][kk] - mx);
  }
  __syncthreads();
  for (int idx = tid; idx < 256; idx += 192) {
    int ss = idx >> 6, i = idx & 63;
    float sum = 0.f, a = 0.f;
#pragma unroll
    for (int kk = 0; kk < 5; ++kk) sum += als[ss][kk];
#pragma unroll
    for (int kk = 0; kk < 5; ++kk) a += als[ss][kk] * hist[ss][kk][i];
    outv[(size_t)(s0 + ss) * 64 + i] = a * rcpf(sum);
  }
}

// ---------------- kernel 5: bilinear fusion X = tanh(ct . Wb . qt + bb) ----------
__global__ __launch_bounds__(256) void k_bilinear(
    const float* __restrict__ ct, const float* __restrict__ qt,
    const float* __restrict__ Wb, const float* __restrict__ bb,
    float* __restrict__ X) {
  const int bn0 = blockIdx.x * 4;
  const int tid = threadIdx.x;
  __shared__ float ctl[4][64], qtl[4][64];
  {
    int ss = tid >> 6, i = tid & 63;
    ctl[ss][i] = ct[(size_t)(bn0 + ss) * 64 + i];
    qtl[ss][i] = qt[(size_t)(bn0 + ss) * 64 + i];
  }
  __syncthreads();
  const int o = tid >> 2, part = tid & 3, j0 = part << 4;
  float qr[4][16];
#pragma unroll
  for (int pp = 0; pp < 4; ++pp)
#pragma unroll
    for (int q = 0; q < 16; ++q) qr[pp][q] = qtl[pp][j0 + q];
  float acc[4] = {0.f, 0.f, 0.f, 0.f};
  const float* wb = Wb + (size_t)o * 4096 + j0;
  for (int i = 0; i < 64; ++i) {
    const float4* w4 = (const float4*)(wb + i * 64);
    float tmp[4] = {0.f, 0.f, 0.f, 0.f};
#pragma unroll
    for (int q = 0; q < 4; ++q) {
      float4 w = w4[q];
#pragma unroll
      for (int pp = 0; pp < 4; ++pp)
        tmp[pp] += w.x * qr[pp][4 * q]     + w.y * qr[pp][4 * q + 1]
                 + w.z * qr[pp][4 * q + 2] + w.w * qr[pp][4 * q + 3];
    }
#pragma unroll
    for (int pp = 0; pp < 4; ++pp) acc[pp] += ctl[pp][i] * tmp[pp];
  }
#pragma unroll
  for (int pp = 0; pp < 4; ++pp) {
    acc[pp] += __shfl_xor(acc[pp], 1);
    acc[pp] += __shfl_xor(acc[pp], 2);
  }
  if (part == 0) {
    float bbv = bb[o];
#pragma unroll
    for (int pp = 0; pp < 4; ++pp)
      X[(size_t)(bn0 + pp) * 64 + o] = tanh_fast(acc[pp] + bbv);
  }
}

// ---------------- kernel 6: GAT layer 1, per (b, head, n-half) ----------
__global__ __launch_bounds__(256) void k_gat1(
    const float* __restrict__ X, const float* __restrict__ W1,
    const float* __restrict__ a1, const float* __restrict__ adj,
    float* __restrict__ X2) {
  const int bid = blockIdx.x;
  const int b = bid >> 4, k = (bid >> 1) & 7, nh = bid & 1;
  const int tid = threadIdx.x;
  __shared__ __align__(16) float whd[128][68];
  __shared__ float w1l[64][64];
  __shared__ float d1l[128], d2l[128];
  for (int v = tid; v < 4096; v += 256) w1l[v >> 6][v & 63] = W1[(size_t)k * 4096 + v];
  __syncthreads();
  {
    const int f = tid & 63, ng = tid >> 6;
    const float* Xb = X + (size_t)b * 128 * 64;
    for (int n = ng * 32; n < ng * 32 + 32; ++n) {
      float a = 0.f;
#pragma unroll
      for (int h = 0; h < 64; ++h) a += Xb[n * 64 + h] * w1l[h][f];
      whd[n][f] = a;
    }
  }
  __syncthreads();
  if (tid < 128) {
    const int n = tid;
    float da = 0.f, db = 0.f;
#pragma unroll
    for (int f = 0; f < 64; ++f) {
      float w = whd[n][f];
      da += w * a1[k * 128 + f];
      db += w * a1[k * 128 + 64 + f];
    }
    d1l[n] = da; d2l[n] = db;
  }
  __syncthreads();
  {
    const int n = nh * 64 + (tid & 63), fq = tid >> 6, f0 = fq * 16;
    unsigned long long mlo = 0ull, mhi = 0ull;
    for (int m = 0; m < 64; ++m) if (adj[n * 128 + m] > 0.f)      mlo |= (1ull << m);
    for (int m = 0; m < 64; ++m) if (adj[n * 128 + 64 + m] > 0.f) mhi |= (1ull << m);
    const float d1n = d1l[n];
    float mx = -3.4e38f;
    for (int m = 0; m < 128; ++m) {
      bool on = (m < 64) ? (((mlo >> m) & 1ull) != 0) : (((mhi >> (m - 64)) & 1ull) != 0);
      float e = lrelu(d1n + d2l[m]);
      mx = fmaxf(mx, on ? e : -3.4e38f);
    }
    float sum = 0.f;
    float acc[16];
#pragma unroll
    for (int q = 0; q < 16; ++q) acc[q] = 0.f;
    for (int m = 0; m < 128; ++m) {
      bool on = (m < 64) ? (((mlo >> m) & 1ull) != 0) : (((mhi >> (m - 64)) & 1ull) != 0);
      float w = on ? __expf(lrelu(d1n + d2l[m]) - mx) : 0.f;
      sum += w;
      const float4* wr = (const float4*)&whd[m][f0];
#pragma unroll
      for (int q4 = 0; q4 < 4; ++q4) {
        float4 wv = wr[q4];
        acc[4 * q4]     += w * wv.x;
        acc[4 * q4 + 1] += w * wv.y;
        acc[4 * q4 + 2] += w * wv.z;
        acc[4 * q4 + 3] += w * wv.w;
      }
    }
    float inv = rcpf(sum);
    float* dst = X2 + ((size_t)b * 128 + n) * 512 + k * 64 + f0;
#pragma unroll
    for (int q = 0; q < 16; ++q) {
      float v = acc[q] * inv;
      dst[q] = v > 0.f ? v : (__expf(v) - 1.f);
    }
  }
}

// ---------------- kernel 7: Wh2 = X2@W2, a2 dots, out1 head ----------
__global__ __launch_bounds__(256) void k_wh2(
    const float* __restrict__ X, const float* __restrict__ Wx, const float* __restrict__ bx,
    const float* __restrict__ X2, const float* __restrict__ W2, const float* __restrict__ a2,
    float* __restrict__ out1g, float* __restrict__ wh2g,
    float* __restrict__ d2ag, float* __restrict__ d2bg) {
  const int b = blockIdx.x >> 3, nq = blockIdx.x & 7;
  const int tid = threadIdx.x;
  __shared__ float w2l[1024];
  for (int v = tid; v < 1024; v += 256) w2l[v] = W2[v];
  __syncthreads();
  const int w = tid >> 6, l = tid & 63;
  const float a20 = a2[0], a21 = a2[1], a22 = a2[2], a23 = a2[3];
#pragma unroll
  for (int it = 0; it < 4; ++it) {
    int n = nq * 16 + w * 4 + it;
    int bn = b * 128 + n;
    const float* xr = X2 + (size_t)bn * 512 + l * 8;
    float4 xa = *(const float4*)xr;
    float4 xb = *(const float4*)(xr + 4);
    float xs[8] = {xa.x, xa.y, xa.z, xa.w, xb.x, xb.y, xb.z, xb.w};
    float s0 = 0.f, s1 = 0.f;
#pragma unroll
    for (int j = 0; j < 8; ++j) {
      s0 += xs[j] * w2l[(l * 8 + j) * 2];
      s1 += xs[j] * w2l[(l * 8 + j) * 2 + 1];
    }
#pragma unroll
    for (int d = 1; d < 64; d <<= 1) { s0 += __shfl_xor(s0, d); s1 += __shfl_xor(s1, d); }
    if (l == 0) {
      wh2g[bn * 2] = s0; wh2g[bn * 2 + 1] = s1;
      d2ag[bn] = s0 * a20 + s1 * a21;
      d2bg[bn] = s0 * a22 + s1 * a23;
    }
  }
  if (tid < 32) {
    int n = nq * 16 + (tid >> 1), c = tid & 1;
    int bn = b * 128 + n;
    const float* xrow = X + (size_t)bn * 64;
    float a = 0.f;
#pragma unroll
    for (int h = 0; h < 64; ++h) a += xrow[h] * Wx[(n * 2 + c) * 64 + h];
    out1g[bn * 2 + c] = tanh_fast(a + bx[n * 2 + c]);
  }
}

// ---------------- kernel 8: GAT layer 2 softmax + residual -> fp32 out [B,C,N] ----------
__global__ __launch_bounds__(128) void k_final(
    const float* __restrict__ adj, const float* __restrict__ wh2g,
    const float* __restrict__ d2ag, const float* __restrict__ d2bg,
    const float* __restrict__ out1g, float* __restrict__ out) {
  const int b = blockIdx.x;
  const int tid = threadIdx.x;
  __shared__ float wh2l[128][2];
  __shared__ float dbl_[128];
  wh2l[tid][0] = wh2g[(size_t)(b * 128 + tid) * 2];
  wh2l[tid][1] = wh2g[(size_t)(b * 128 + tid) * 2 + 1];
  dbl_[tid] = d2bg[b * 128 + tid];
  __syncthreads();
  const int n = tid;
  unsigned long long mlo = 0ull, mhi = 0ull;
  for (int m = 0; m < 64; ++m) if (adj[n * 128 + m] > 0.f)      mlo |= (1ull << m);
  for (int m = 0; m < 64; ++m) if (adj[n * 128 + 64 + m] > 0.f) mhi |= (1ull << m);
  const float dan = d2ag[b * 128 + n];
  float mx = -3.4e38f;
  for (int m = 0; m < 128; ++m) {
    bool on = (m < 64) ? (((mlo >> m) & 1ull) != 0) : (((mhi >> (m - 64)) & 1ull) != 0);
    float e = lrelu(dan + dbl_[m]);
    mx = fmaxf(mx, on ? e : -3.4e38f);
  }
  float sum = 0.f, x0 = 0.f, x1 = 0.f;
  for (int m = 0; m < 128; ++m) {
    bool on = (m < 64) ? (((mlo >> m) & 1ull) != 0) : (((mhi >> (m - 64)) & 1ull) != 0);
    float w = on ? __expf(lrelu(dan + dbl_[m]) - mx) : 0.f;
    sum += w; x0 += w * wh2l[m][0]; x1 += w * wh2l[m][1];
  }
  float inv = rcpf(sum);
  out[(size_t)(b * 2 + 0) * 128 + n] = x0 * inv + out1g[(size_t)(b * 128 + n) * 2];
  out[(size_t)(b * 2 + 1) * 128 + n] = x1 * inv + out1g[(size_t)(b * 128 + n) * 2 + 1];
}

} // namespace

extern "C" void kernel_launch(void* const* d_in, const int* in_sizes, int n_in,
                              void* d_out, int out_size, void* d_ws, size_t ws_size,
                              hipStream_t stream) {
  (void)in_sizes; (void)n_in; (void)out_size;
  const float* s      = (const float*)d_in[0];
  const float* p      = (const float*)d_in[1];
  const float* adj    = (const float*)d_in[2];
  const float* sm1_Wi = (const float*)d_in[3];
  const float* sm1_Wh = (const float*)d_in[4];
  const float* sm1_bi = (const float*)d_in[5];
  const float* sm1_bh = (const float*)d_in[6];
  const float* sm2_Wi = (const float*)d_in[7];
  const float* sm2_Wh = (const float*)d_in[8];
  const float* sm2_bi = (const float*)d_in[9];
  const float* sm2_bh = (const float*)d_in[10];
  const float* pr_Wi  = (const float*)d_in[11];
  const float* pr_Wh  = (const float*)d_in[12];
  const float* pr_bi  = (const float*)d_in[13];
  const float* pr_bh  = (const float*)d_in[14];
  const float* Wb     = (const float*)d_in[15];
  const float* bb     = (const float*)d_in[16];
  const float* Wx     = (const float*)d_in[17];
  const float* bx     = (const float*)d_in[18];
  const float* W1     = (const float*)d_in[19];
  const float* a1     = (const float*)d_in[20];
  const float* W2     = (const float*)d_in[21];
  const float* a2     = (const float*)d_in[22];

  // workspace layout (bytes); total = 43,540,480
  if (ws_size < 43540480u) return;
  char* ws = (char*)d_ws;
  _Float16* gx1  = (_Float16*)ws;              // 39,321,600 (scan-layout fp16)
  _Float16* cvh  = (_Float16*)(ws + 39321600); // 655,360 (fp16 cv, [seq][t][64])
  float* ct      = (float*)(ws + 40632320);    // 262,144
  float* qt      = (float*)(ws + 40894464);    // 262,144
  float* X       = (float*)(ws + 41156608);    // 262,144
  float* X2      = (float*)(ws + 41418752);    // 2,097,152
  _Float16* Bt   = (_Float16*)(ws + 41418752); // 147,456 (dead before X2 written)
  float* wh2g    = (float*)(ws + 43515904);    // 8,192
  float* out1g   = (float*)(ws + 43524096);    // 8,192
  float* d2ag    = (float*)(ws + 43532288);    // 4,096
  float* d2bg    = (float*)(ws + 43536384);    // 4,096

  hipLaunchKernelGGL(k_cvtB,     dim3(288),  dim3(256), 0, stream, sm1_Wi, Bt);
  hipLaunchKernelGGL(k_gx1,      dim3(800),  dim3(256), 0, stream, s, Bt, sm1_bi, gx1);
  hipLaunchKernelGGL(k_scan1m,   dim3(320),  dim3(64),  0, stream, gx1, sm1_Wh, sm1_bh, cvh);
  hipLaunchKernelGGL(k_scan2m,   dim3(64),   dim3(64),  0, stream, cvh, sm2_Wi, sm2_Wh, sm2_bi, sm2_bh, ct);
  hipLaunchKernelGGL(k_scan3,    dim3(256),  dim3(192), 0, stream, p, pr_Wi, pr_Wh, pr_bi, pr_bh, qt);
  hipLaunchKernelGGL(k_bilinear, dim3(256),  dim3(256), 0, stream, ct, qt, Wb, bb, X);
  hipLaunchKernelGGL(k_gat1,     dim3(128),  dim3(256), 0, stream, X, W1, a1, adj, X2);
  hipLaunchKernelGGL(k_wh2,      dim3(64),   dim3(256), 0, stream, X, Wx, bx, X2, W2, a2, out1g, wh2g, d2ag, d2bg);
  hipLaunchKernelGGL(k_final,    dim3(8),    dim3(128), 0, stream, adj, wh2g, d2ag, d2bg, out1g, (float*)d_out);
}

// Round 6
// 469.207 us; speedup vs baseline: 1.6085x; 1.0155x over previous
//
#include <hip/hip_runtime.h>
#include <hip/hip_bf16.h>
#include <hip/hip_fp16.h>

#define DI __device__ __forceinline__

namespace {

constexpr int G_  = 192;    // 3*H
constexpr int FT_ = 384;

typedef _Float16 f16x8 __attribute__((ext_vector_type(8)));
typedef _Float16 f16x4 __attribute__((ext_vector_type(4)));
typedef float    f32x4 __attribute__((ext_vector_type(4)));

DI float rcpf(float x) { return __builtin_amdgcn_rcpf(x); }
DI float lrelu(float x) { return x > 0.f ? x : 0.2f * x; }
DI float sigmoidf(float x) { return rcpf(1.f + __expf(-x)); }
DI float tanh_fast(float x) { return 1.f - 2.f * rcpf(__expf(2.f * x) + 1.f); }

// ---------------- kernel 0: Bt[g][f] = fp16(Wi[f][g]) ----------
__global__ __launch_bounds__(256) void k_cvtB(
    const float* __restrict__ Wi, _Float16* __restrict__ Bt) {
  int v = blockIdx.x * 256 + threadIdx.x;   // 73728 = 192*384
  int g = v / 384, f = v % 384;
  Bt[v] = (_Float16)Wi[f * 192 + g];
}

// ---------------- kernel 1: gx1 = s_slab^T @ Wi + bi via fp16 MFMA ----------
__global__ __launch_bounds__(256) void k_gx1(
    const float* __restrict__ s, const _Float16* __restrict__ Bt,
    const float* __restrict__ bi, _Float16* __restrict__ gx1) {
  const int slab = blockIdx.x;
  const int b = slab / 100, rem = slab % 100, t = rem / 20, k = rem % 20;
  const float* A = s + (size_t)((b * 5 + t) * 20 + k) * (FT_ * 128);  // [f][n]
  __shared__ __align__(16) _Float16 AsL[128 * 40];
  __shared__ __align__(16) _Float16 BsL[192 * 40];
  __shared__ __align__(16) float bisL[192];
  const int tid = threadIdx.x;
  if (tid < 192) bisL[tid] = bi[tid];
  const int w = tid >> 6, l = tid & 63;
  const int lr = l & 15, lk = l >> 4;

  f32x4 acc[12][2];
#pragma unroll
  for (int gt = 0; gt < 12; ++gt)
#pragma unroll
    for (int nt = 0; nt < 2; ++nt) acc[gt][nt] = (f32x4){0.f, 0.f, 0.f, 0.f};

  for (int kc = 0; kc < 12; ++kc) {
    const int f0 = kc * 32;
#pragma unroll
    for (int pass = 0; pass < 2; ++pass) {
      int task = tid + 256 * pass;
      int n = task & 127, oct = task >> 7;
      const float* src = A + (size_t)(f0 + oct * 8) * 128 + n;
      float v[8];
#pragma unroll
      for (int j = 0; j < 8; ++j) v[j] = src[j * 128];
      f16x8 h;
#pragma unroll
      for (int j = 0; j < 8; ++j) h[j] = (_Float16)v[j];
      *(f16x8*)&AsL[n * 40 + oct * 8] = h;
    }
#pragma unroll
    for (int pass = 0; pass < 3; ++pass) {
      int c = tid + 256 * pass;
      int g = c >> 2, oct = c & 3;
      f16x8 h = *(const f16x8*)&Bt[(size_t)g * 384 + f0 + oct * 8];
      *(f16x8*)&BsL[g * 40 + oct * 8] = h;
    }
    __syncthreads();
    f16x8 aN[2];
#pragma unroll
    for (int nt = 0; nt < 2; ++nt)
      aN[nt] = *(const f16x8*)&AsL[(w * 32 + nt * 16 + lr) * 40 + lk * 8];
#pragma unroll
    for (int gt = 0; gt < 12; ++gt) {
      f16x8 bW = *(const f16x8*)&BsL[(gt * 16 + lr) * 40 + lk * 8];
      acc[gt][0] = __builtin_amdgcn_mfma_f32_16x16x32_f16(bW, aN[0], acc[gt][0], 0, 0, 0);
      acc[gt][1] = __builtin_amdgcn_mfma_f32_16x16x32_f16(bW, aN[1], acc[gt][1], 0, 0, 0);
    }
    __syncthreads();
  }
  const size_t base3 = ((size_t)k * 40 + b * 5 + t) * 8;
#pragma unroll
  for (int nt = 0; nt < 2; ++nt) {
    const int ngrp = w * 2 + nt;
    _Float16* dstbase = gx1 + ((base3 + ngrp) * 3) * 1024 + (size_t)l * 16;
#pragma unroll
    for (int gate = 0; gate < 3; ++gate) {
      f16x8 h0, h1;
#pragma unroll
      for (int tq = 0; tq < 4; ++tq) {
        const int gt = gate * 4 + tq;
        f32x4 bias = *(const f32x4*)&bisL[gt * 16 + lk * 4];
        f32x4 c = acc[gt][nt];
#pragma unroll
        for (int r = 0; r < 4; ++r) {
          float v = c[r] + bias[r];
          if (tq < 2) h0[tq * 4 + r] = (_Float16)v;
          else        h1[(tq - 2) * 4 + r] = (_Float16)v;
        }
      }
      *(f16x8*)(dstbase + (size_t)gate * 1024) = h0;
      *(f16x8*)(dstbase + (size_t)gate * 1024 + 8) = h1;
    }
  }
}

// ---------------- kernel 2: SM1 GRU scan via MFMA, wave-autonomous ----------
__global__ __launch_bounds__(64, 1) void k_scan1m(
    const _Float16* __restrict__ gx, const float* __restrict__ Wh,
    const float* __restrict__ bh, _Float16* __restrict__ cvh) {
  const int wv = blockIdx.x;           // 0..319
  const int b = wv / 40, rem = wv % 40, t = rem / 8, ng = rem % 8;
  const int l = threadIdx.x;
  const int seq = l & 15, rg = l >> 4;

  __shared__ __align__(16) _Float16 histL[20][64][24];
  __shared__ __align__(16) _Float16 red[16][72];

  f16x8 whF[12][2];
#pragma unroll
  for (int gt = 0; gt < 12; ++gt)
#pragma unroll
    for (int c = 0; c < 2; ++c) {
      f16x8 h;
#pragma unroll
      for (int j = 0; j < 8; ++j)
        h[j] = (_Float16)Wh[(size_t)(32 * c + rg * 8 + j) * 192 + gt * 16 + seq];
      whF[gt][c] = h;
    }
  f32x4 bhF[12];
#pragma unroll
  for (int gt = 0; gt < 12; ++gt)
    bhF[gt] = *(const f32x4*)&bh[gt * 16 + rg * 4];

  float h16[16];
#pragma unroll
  for (int j = 0; j < 16; ++j) h16[j] = 0.f;

#define GXP(kk) (gx + ((((size_t)(kk) * 40 + b * 5 + t) * 8 + ng) * 3) * 1024 + (size_t)l * 16)

  f16x8 gxc[3][2], gxn[3][2], gxn2[3][2];
  {
    const _Float16* p0 = GXP(0);
    const _Float16* p1 = GXP(1);
    const _Float16* p2 = GXP(2);
#pragma unroll
    for (int g = 0; g < 3; ++g) {
      gxc[g][0]  = *(const f16x8*)(p0 + g * 1024);
      gxc[g][1]  = *(const f16x8*)(p0 + g * 1024 + 8);
      gxn[g][0]  = *(const f16x8*)(p1 + g * 1024);
      gxn[g][1]  = *(const f16x8*)(p1 + g * 1024 + 8);
      gxn2[g][0] = *(const f16x8*)(p2 + g * 1024);
      gxn2[g][1] = *(const f16x8*)(p2 + g * 1024 + 8);
    }
  }

  f16x8 bf0, bf1;
  f32x4 acc[12];

#define GATES_AND_H(KCONST_HIST)                                               \
  {                                                                            \
    _Float16* hp = &histL[KCONST_HIST][l][0];                                  \
    f16x8 p0, p1;                                                              \
    _Pragma("unroll")                                                          \
    for (int tq = 0; tq < 4; ++tq) {                                           \
      _Pragma("unroll")                                                        \
      for (int r = 0; r < 4; ++r) {                                            \
        const int idx = tq * 4 + r;                                            \
        float xr = (float)gxc[0][idx >> 3][idx & 7];                           \
        float xz = (float)gxc[1][idx >> 3][idx & 7];                           \
        float xn = (float)gxc[2][idx >> 3][idx & 7];                           \
        float hr = acc[tq][r], hz = acc[4 + tq][r], hnv = acc[8 + tq][r];      \
        float rr = sigmoidf(xr + hr);                                          \
        float zz = sigmoidf(xz + hz);                                          \
        float nn = tanh_fast(xn + rr * hnv);                                   \
        float hv = (1.f - zz) * nn + zz * h16[idx];                            \
        h16[idx] = hv;                                                         \
        if (idx < 8) p0[idx] = (_Float16)hv; else p1[idx - 8] = (_Float16)hv;  \
      }                                                                        \
    }                                                                          \
    *(f16x8*)hp = p0;                                                          \
    *(f16x8*)(hp + 8) = p1;                                                    \
  }

#define REDIST()                                                               \
  {                                                                            \
    _Pragma("unroll")                                                          \
    for (int tq = 0; tq < 4; ++tq) {                                           \
      f16x4 q;                                                                 \
      q[0] = (_Float16)h16[tq * 4 + 0]; q[1] = (_Float16)h16[tq * 4 + 1];      \
      q[2] = (_Float16)h16[tq * 4 + 2]; q[3] = (_Float16)h16[tq * 4 + 3];      \
      *(f16x4*)&red[seq][16 * tq + 4 * rg] = q;                                \
    }                                                                          \
    bf0 = *(const f16x8*)&red[seq][8 * rg];                                    \
    bf1 = *(const f16x8*)&red[seq][32 + 8 * rg];                               \
  }

  // ---- k = 0 ----
#pragma unroll
  for (int gt = 0; gt < 12; ++gt) acc[gt] = bhF[gt];
  GATES_AND_H(0)
  REDIST()

  // ---- k = 1..18 (prefetch depth 2) ----
  for (int k = 1; k < 19; ++k) {
#pragma unroll
    for (int g = 0; g < 3; ++g) {
      gxc[g][0] = gxn[g][0];  gxc[g][1] = gxn[g][1];
      gxn[g][0] = gxn2[g][0]; gxn[g][1] = gxn2[g][1];
    }
    if (k < 18) {
      const _Float16* pn = GXP(k + 2);
#pragma unroll
      for (int g = 0; g < 3; ++g) {
        gxn2[g][0] = *(const f16x8*)(pn + g * 1024);
        gxn2[g][1] = *(const f16x8*)(pn + g * 1024 + 8);
      }
    }
#pragma unroll
    for (int gt = 0; gt < 12; ++gt) {
      acc[gt] = bhF[gt];
      acc[gt] = __builtin_amdgcn_mfma_f32_16x16x32_f16(whF[gt][0], bf0, acc[gt], 0, 0, 0);
      acc[gt] = __builtin_amdgcn_mfma_f32_16x16x32_f16(whF[gt][1], bf1, acc[gt], 0, 0, 0);
    }
    GATES_AND_H(k)
    REDIST()
  }

  // ---- k = 19 ----
#pragma unroll
  for (int g = 0; g < 3; ++g) { gxc[g][0] = gxn[g][0]; gxc[g][1] = gxn[g][1]; }
#pragma unroll
  for (int gt = 0; gt < 12; ++gt) {
    acc[gt] = bhF[gt];
    acc[gt] = __builtin_amdgcn_mfma_f32_16x16x32_f16(whF[gt][0], bf0, acc[gt], 0, 0, 0);
    acc[gt] = __builtin_amdgcn_mfma_f32_16x16x32_f16(whF[gt][1], bf1, acc[gt], 0, 0, 0);
  }
  GATES_AND_H(19)

  // ---- temporal attention ----
  float d[20];
#pragma unroll
  for (int kk = 0; kk < 20; ++kk) {
    f16x8 a0 = *(const f16x8*)&histL[kk][l][0];
    f16x8 a1 = *(const f16x8*)&histL[kk][l][8];
    float p = 0.f;
#pragma unroll
    for (int j = 0; j < 8; ++j)
      p += (float)a0[j] * h16[j] + (float)a1[j] * h16[8 + j];
    p += __shfl_xor(p, 16);
    p += __shfl_xor(p, 32);
    d[kk] = p;
  }
  float mx = d[0];
#pragma unroll
  for (int kk = 1; kk < 20; ++kk) mx = fmaxf(mx, d[kk]);
  float sum = 0.f;
#pragma unroll
  for (int kk = 0; kk < 20; ++kk) { d[kk] = __expf(d[kk] - mx); sum += d[kk]; }
  const float inv = rcpf(sum);
  float av[16];
#pragma unroll
  for (int j = 0; j < 16; ++j) av[j] = 0.f;
#pragma unroll
  for (int kk = 0; kk < 20; ++kk) {
    f16x8 a0 = *(const f16x8*)&histL[kk][l][0];
    f16x8 a1 = *(const f16x8*)&histL[kk][l][8];
    float wgt = d[kk] * inv;
#pragma unroll
    for (int j = 0; j < 8; ++j) {
      av[j]     += wgt * (float)a0[j];
      av[8 + j] += wgt * (float)a1[j];
    }
  }
  const int n = ng * 16 + seq;
  const size_t seqg = (size_t)b * 128 + n;
  _Float16* dst = cvh + (seqg * 5 + t) * 64;
#pragma unroll
  for (int tq = 0; tq < 4; ++tq) {
    f16x4 q;
    q[0] = (_Float16)av[tq * 4 + 0]; q[1] = (_Float16)av[tq * 4 + 1];
    q[2] = (_Float16)av[tq * 4 + 2]; q[3] = (_Float16)av[tq * 4 + 3];
    *(f16x4*)&dst[16 * tq + 4 * rg] = q;
  }
#undef GXP
#undef GATES_AND_H
#undef REDIST
}

// ---------------- kernel 3: SM2 GRU scan + price GRU scan (merged, MFMA) ----------
// blocks 0..63: SM2 (cvh -> ct).  blocks 64..127: price (p -> qt).
__global__ __launch_bounds__(64, 1) void k_scan23(
    const _Float16* __restrict__ cvh, const float* __restrict__ Wi2,
    const float* __restrict__ Wh2w, const float* __restrict__ bi2,
    const float* __restrict__ bh2, float* __restrict__ ct,
    const float* __restrict__ p, const float* __restrict__ Wi3,
    const float* __restrict__ Wh3, const float* __restrict__ bi3,
    const float* __restrict__ bh3, float* __restrict__ qt) {
  const int l = threadIdx.x;
  const int seq = l & 15, rg = l >> 4;

  __shared__ __align__(16) _Float16 histL[5][64][24];
  __shared__ __align__(16) _Float16 red[16][72];
  __shared__ float wi3L[576];
  __shared__ float bi3L[192];
  __shared__ float x3L[240];   // [t][f][seq]

  const bool isPrice = blockIdx.x >= 64;
  const size_t seqg0 = (size_t)(isPrice ? blockIdx.x - 64 : blockIdx.x) * 16;
  const float* Wh = isPrice ? Wh3 : Wh2w;
  const float* bh = isPrice ? bh3 : bh2;

  f16x8 whF[12][2];
#pragma unroll
  for (int gt = 0; gt < 12; ++gt)
#pragma unroll
    for (int c = 0; c < 2; ++c) {
      f16x8 hh;
#pragma unroll
      for (int j = 0; j < 8; ++j)
        hh[j] = (_Float16)Wh[(size_t)(32 * c + rg * 8 + j) * 192 + gt * 16 + seq];
      whF[gt][c] = hh;
    }
  f32x4 bhF[12];
#pragma unroll
  for (int gt = 0; gt < 12; ++gt)
    bhF[gt] = *(const f32x4*)&bh[gt * 16 + rg * 4];

  // SM2-only: Wi fragments.  Price-only: stage Wi3/bi3/x into LDS.
  f16x8 wiF[12][2];
  f32x4 biF[12];
  if (!isPrice) {
#pragma unroll
    for (int gt = 0; gt < 12; ++gt)
#pragma unroll
      for (int c = 0; c < 2; ++c) {
        f16x8 hi;
#pragma unroll
        for (int j = 0; j < 8; ++j)
          hi[j] = (_Float16)Wi2[(size_t)(32 * c + rg * 8 + j) * 192 + gt * 16 + seq];
        wiF[gt][c] = hi;
      }
#pragma unroll
    for (int gt = 0; gt < 12; ++gt)
      biF[gt] = *(const f32x4*)&bi2[gt * 16 + rg * 4];
  } else {
    const int b = (int)(seqg0 >> 7), n0 = (int)(seqg0 & 127);
    for (int idx = l; idx < 576; idx += 64) wi3L[idx] = Wi3[idx];
    for (int idx = l; idx < 192; idx += 64) bi3L[idx] = bi3[idx];
    for (int idx = l; idx < 240; idx += 64) {
      int t = idx / 48, r = idx % 48, f = r / 16, sq = r % 16;
      x3L[idx] = p[((size_t)(b * 5 + t) * 3 + f) * 128 + n0 + sq];
    }
    __syncthreads();
  }

  float h16[16];
#pragma unroll
  for (int j = 0; j < 16; ++j) h16[j] = 0.f;
  f16x8 bf0, bf1;

#pragma unroll
  for (int t = 0; t < 5; ++t) {
    f32x4 accX[12], accH[12];
    if (!isPrice) {
      const _Float16* xp = cvh + ((seqg0 + seq) * 5 + t) * 64;
      f16x8 xf0 = *(const f16x8*)(xp + 8 * rg);
      f16x8 xf1 = *(const f16x8*)(xp + 32 + 8 * rg);
#pragma unroll
      for (int gt = 0; gt < 12; ++gt) {
        accX[gt] = biF[gt];
        accX[gt] = __builtin_amdgcn_mfma_f32_16x16x32_f16(wiF[gt][0], xf0, accX[gt], 0, 0, 0);
        accX[gt] = __builtin_amdgcn_mfma_f32_16x16x32_f16(wiF[gt][1], xf1, accX[gt], 0, 0, 0);
      }
    } else {
      const float x0 = x3L[t * 48 + seq];
      const float x1 = x3L[t * 48 + 16 + seq];
      const float x2 = x3L[t * 48 + 32 + seq];
#pragma unroll
      for (int G = 0; G < 3; ++G)
#pragma unroll
        for (int tq = 0; tq < 4; ++tq) {
          f32x4 v;
#pragma unroll
          for (int r = 0; r < 4; ++r) {
            const int g = G * 64 + 16 * tq + 4 * rg + r;
            v[r] = bi3L[g] + wi3L[g] * x0 + wi3L[192 + g] * x1 + wi3L[384 + g] * x2;
          }
          accX[G * 4 + tq] = v;
        }
    }
#pragma unroll
    for (int gt = 0; gt < 12; ++gt) {
      accH[gt] = bhF[gt];
      if (t > 0) {
        accH[gt] = __builtin_amdgcn_mfma_f32_16x16x32_f16(whF[gt][0], bf0, accH[gt], 0, 0, 0);
        accH[gt] = __builtin_amdgcn_mfma_f32_16x16x32_f16(whF[gt][1], bf1, accH[gt], 0, 0, 0);
      }
    }
    _Float16* hp = &histL[t][l][0];
    f16x8 p0, p1;
#pragma unroll
    for (int tq = 0; tq < 4; ++tq) {
#pragma unroll
      for (int r = 0; r < 4; ++r) {
        const int idx = tq * 4 + r;
        float xr = accX[tq][r], xz = accX[4 + tq][r], xn = accX[8 + tq][r];
        float hr = accH[tq][r], hz = accH[4 + tq][r], hnv = accH[8 + tq][r];
        float rr = sigmoidf(xr + hr);
        float zz = sigmoidf(xz + hz);
        float nn = tanh_fast(xn + rr * hnv);
        float hv = (1.f - zz) * nn + zz * h16[idx];
        h16[idx] = hv;
        if (idx < 8) p0[idx] = (_Float16)hv; else p1[idx - 8] = (_Float16)hv;
      }
    }
    *(f16x8*)hp = p0;
    *(f16x8*)(hp + 8) = p1;
    if (t < 4) {
#pragma unroll
      for (int tq = 0; tq < 4; ++tq) {
        f16x4 q;
        q[0] = (_Float16)h16[tq * 4 + 0]; q[1] = (_Float16)h16[tq * 4 + 1];
        q[2] = (_Float16)h16[tq * 4 + 2]; q[3] = (_Float16)h16[tq * 4 + 3];
        *(f16x4*)&red[seq][16 * tq + 4 * rg] = q;
      }
      bf0 = *(const f16x8*)&red[seq][8 * rg];
      bf1 = *(const f16x8*)&red[seq][32 + 8 * rg];
    }
  }

  // attention over 5 steps
  float d[5];
#pragma unroll
  for (int kk = 0; kk < 5; ++kk) {
    f16x8 a0 = *(const f16x8*)&histL[kk][l][0];
    f16x8 a1 = *(const f16x8*)&histL[kk][l][8];
    float pq = 0.f;
#pragma unroll
    for (int j = 0; j < 8; ++j)
      pq += (float)a0[j] * h16[j] + (float)a1[j] * h16[8 + j];
    pq += __shfl_xor(pq, 16);
    pq += __shfl_xor(pq, 32);
    d[kk] = pq;
  }
  float mx = d[0];
#pragma unroll
  for (int kk = 1; kk < 5; ++kk) mx = fmaxf(mx, d[kk]);
  float sum = 0.f;
#pragma unroll
  for (int kk = 0; kk < 5; ++kk) { d[kk] = __expf(d[kk] - mx); sum += d[kk]; }
  const float inv = rcpf(sum);
  float av[16];
#pragma unroll
  for (int j = 0; j < 16; ++j) av[j] = 0.f;
#pragma unroll
  for (int kk = 0; kk < 5; ++kk) {
    f16x8 a0 = *(const f16x8*)&histL[kk][l][0];
    f16x8 a1 = *(const f16x8*)&histL[kk][l][8];
    float wgt = d[kk] * inv;
#pragma unroll
    for (int j = 0; j < 8; ++j) {
      av[j]     += wgt * (float)a0[j];
      av[8 + j] += wgt * (float)a1[j];
    }
  }
  float* dst = (isPrice ? qt : ct) + (seqg0 + seq) * 64;
#pragma unroll
  for (int tq = 0; tq < 4; ++tq) {
    float4 o = make_float4(av[tq * 4], av[tq * 4 + 1], av[tq * 4 + 2], av[tq * 4 + 3]);
    *(float4*)&dst[16 * tq + 4 * rg] = o;
  }
}

// ---------------- kernel 5: bilinear fusion X = tanh(ct . Wb . qt + bb) ----------
__global__ __launch_bounds__(256) void k_bilinear(
    const float* __restrict__ ct, const float* __restrict__ qt,
    const float* __restrict__ Wb, const float* __restrict__ bb,
    float* __restrict__ X) {
  const int bn0 = blockIdx.x * 4;
  const int tid = threadIdx.x;
  __shared__ float ctl[4][64], qtl[4][64];
  {
    int ss = tid >> 6, i = tid & 63;
    ctl[ss][i] = ct[(size_t)(bn0 + ss) * 64 + i];
    qtl[ss][i] = qt[(size_t)(bn0 + ss) * 64 + i];
  }
  __syncthreads();
  const int o = tid >> 2, part = tid & 3, j0 = part << 4;
  float qr[4][16];
#pragma unroll
  for (int pp = 0; pp < 4; ++pp)
#pragma unroll
    for (int q = 0; q < 16; ++q) qr[pp][q] = qtl[pp][j0 + q];
  float acc[4] = {0.f, 0.f, 0.f, 0.f};
  const float* wb = Wb + (size_t)o * 4096 + j0;
  for (int i = 0; i < 64; ++i) {
    const float4* w4 = (const float4*)(wb + i * 64);
    float tmp[4] = {0.f, 0.f, 0.f, 0.f};
#pragma unroll
    for (int q = 0; q < 4; ++q) {
      float4 w = w4[q];
#pragma unroll
      for (int pp = 0; pp < 4; ++pp)
        tmp[pp] += w.x * qr[pp][4 * q]     + w.y * qr[pp][4 * q + 1]
                 + w.z * qr[pp][4 * q + 2] + w.w * qr[pp][4 * q + 3];
    }
#pragma unroll
    for (int pp = 0; pp < 4; ++pp) acc[pp] += ctl[pp][i] * tmp[pp];
  }
#pragma unroll
  for (int pp = 0; pp < 4; ++pp) {
    acc[pp] += __shfl_xor(acc[pp], 1);
    acc[pp] += __shfl_xor(acc[pp], 2);
  }
  if (part == 0) {
    float bbv = bb[o];
#pragma unroll
    for (int pp = 0; pp < 4; ++pp)
      X[(size_t)(bn0 + pp) * 64 + o] = tanh_fast(acc[pp] + bbv);
  }
}

// ---------------- kernel 6: GAT layer 1, per (b, head, n-half) ----------
__global__ __launch_bounds__(256) void k_gat1(
    const float* __restrict__ X, const float* __restrict__ W1,
    const float* __restrict__ a1, const float* __restrict__ adj,
    float* __restrict__ X2) {
  const int bid = blockIdx.x;
  const int b = bid >> 4, k = (bid >> 1) & 7, nh = bid & 1;
  const int tid = threadIdx.x;
  __shared__ __align__(16) float whd[128][68];
  __shared__ float w1l[64][64];
  __shared__ float d1l[128], d2l[128];
  for (int v = tid; v < 4096; v += 256) w1l[v >> 6][v & 63] = W1[(size_t)k * 4096 + v];
  __syncthreads();
  {
    const int f = tid & 63, ng = tid >> 6;
    const float* Xb = X + (size_t)b * 128 * 64;
    for (int n = ng * 32; n < ng * 32 + 32; ++n) {
      float a = 0.f;
#pragma unroll
      for (int h = 0; h < 64; ++h) a += Xb[n * 64 + h] * w1l[h][f];
      whd[n][f] = a;
    }
  }
  __syncthreads();
  if (tid < 128) {
    const int n = tid;
    float da = 0.f, db = 0.f;
#pragma unroll
    for (int f = 0; f < 64; ++f) {
      float w = whd[n][f];
      da += w * a1[k * 128 + f];
      db += w * a1[k * 128 + 64 + f];
    }
    d1l[n] = da; d2l[n] = db;
  }
  __syncthreads();
  {
    const int n = nh * 64 + (tid & 63), fq = tid >> 6, f0 = fq * 16;
    unsigned long long mlo = 0ull, mhi = 0ull;
    for (int m = 0; m < 64; ++m) if (adj[n * 128 + m] > 0.f)      mlo |= (1ull << m);
    for (int m = 0; m < 64; ++m) if (adj[n * 128 + 64 + m] > 0.f) mhi |= (1ull << m);
    const float d1n = d1l[n];
    float mx = -3.4e38f;
    for (int m = 0; m < 128; ++m) {
      bool on = (m < 64) ? (((mlo >> m) & 1ull) != 0) : (((mhi >> (m - 64)) & 1ull) != 0);
      float e = lrelu(d1n + d2l[m]);
      mx = fmaxf(mx, on ? e : -3.4e38f);
    }
    float sum = 0.f;
    float acc[16];
#pragma unroll
    for (int q = 0; q < 16; ++q) acc[q] = 0.f;
    for (int m = 0; m < 128; ++m) {
      bool on = (m < 64) ? (((mlo >> m) & 1ull) != 0) : (((mhi >> (m - 64)) & 1ull) != 0);
      float w = on ? __expf(lrelu(d1n + d2l[m]) - mx) : 0.f;
      sum += w;
      const float4* wr = (const float4*)&whd[m][f0];
#pragma unroll
      for (int q4 = 0; q4 < 4; ++q4) {
        float4 wv = wr[q4];
        acc[4 * q4]     += w * wv.x;
        acc[4 * q4 + 1] += w * wv.y;
        acc[4 * q4 + 2] += w * wv.z;
        acc[4 * q4 + 3] += w * wv.w;
      }
    }
    float inv = rcpf(sum);
    float* dst = X2 + ((size_t)b * 128 + n) * 512 + k * 64 + f0;
#pragma unroll
    for (int q = 0; q < 16; ++q) {
      float v = acc[q] * inv;
      dst[q] = v > 0.f ? v : (__expf(v) - 1.f);
    }
  }
}

// ---------------- kernel 7: merged head (out1, Wh2=X2@W2, GAT2 softmax, residual) ----------
__global__ __launch_bounds__(256) void k_head(
    const float* __restrict__ X, const float* __restrict__ Wx, const float* __restrict__ bx,
    const float* __restrict__ X2, const float* __restrict__ W2, const float* __restrict__ a2,
    const float* __restrict__ adj, float* __restrict__ out) {
  const int b = blockIdx.x;
  const int tid = threadIdx.x;
  __shared__ float w2l[1024];
  __shared__ float wh2l[128][2];
  __shared__ float d2aL[128], d2bL[128];
  __shared__ float out1L[128][2];
  for (int v = tid; v < 1024; v += 256) w2l[v] = W2[v];
  __syncthreads();
  const int w = tid >> 6, l = tid & 63;
  const float a20 = a2[0], a21 = a2[1], a22 = a2[2], a23 = a2[3];
  for (int it = 0; it < 32; ++it) {
    int n = w * 32 + it;
    const float* xr = X2 + ((size_t)b * 128 + n) * 512 + l * 8;
    float4 xa = *(const float4*)xr;
    float4 xb = *(const float4*)(xr + 4);
    float xs[8] = {xa.x, xa.y, xa.z, xa.w, xb.x, xb.y, xb.z, xb.w};
    float s0 = 0.f, s1 = 0.f;
#pragma unroll
    for (int j = 0; j < 8; ++j) {
      s0 += xs[j] * w2l[(l * 8 + j) * 2];
      s1 += xs[j] * w2l[(l * 8 + j) * 2 + 1];
    }
#pragma unroll
    for (int d = 1; d < 64; d <<= 1) { s0 += __shfl_xor(s0, d); s1 += __shfl_xor(s1, d); }
    if (l == 0) {
      wh2l[n][0] = s0; wh2l[n][1] = s1;
      d2aL[n] = s0 * a20 + s1 * a21;
      d2bL[n] = s0 * a22 + s1 * a23;
    }
  }
  if (tid < 128) {
    int n = tid;
    const float* xrow = X + ((size_t)b * 128 + n) * 64;
#pragma unroll
    for (int c = 0; c < 2; ++c) {
      float a = 0.f;
#pragma unroll
      for (int h = 0; h < 64; ++h) a += xrow[h] * Wx[(n * 2 + c) * 64 + h];
      out1L[n][c] = tanh_fast(a + bx[n * 2 + c]);
    }
  }
  __syncthreads();
  if (tid < 128) {
    const int n = tid;
    unsigned long long mlo = 0ull, mhi = 0ull;
    for (int m = 0; m < 64; ++m) if (adj[n * 128 + m] > 0.f)      mlo |= (1ull << m);
    for (int m = 0; m < 64; ++m) if (adj[n * 128 + 64 + m] > 0.f) mhi |= (1ull << m);
    const float dan = d2aL[n];
    float mx = -3.4e38f;
    for (int m = 0; m < 128; ++m) {
      bool on = (m < 64) ? (((mlo >> m) & 1ull) != 0) : (((mhi >> (m - 64)) & 1ull) != 0);
      float e = lrelu(dan + d2bL[m]);
      mx = fmaxf(mx, on ? e : -3.4e38f);
    }
    float sum = 0.f, x0 = 0.f, x1 = 0.f;
    for (int m = 0; m < 128; ++m) {
      bool on = (m < 64) ? (((mlo >> m) & 1ull) != 0) : (((mhi >> (m - 64)) & 1ull) != 0);
      float wgt = on ? __expf(lrelu(dan + d2bL[m]) - mx) : 0.f;
      sum += wgt; x0 += wgt * wh2l[m][0]; x1 += wgt * wh2l[m][1];
    }
    float inv = rcpf(sum);
    out[(size_t)(b * 2 + 0) * 128 + n] = x0 * inv + out1L[n][0];
    out[(size_t)(b * 2 + 1) * 128 + n] = x1 * inv + out1L[n][1];
  }
}

} // namespace

extern "C" void kernel_launch(void* const* d_in, const int* in_sizes, int n_in,
                              void* d_out, int out_size, void* d_ws, size_t ws_size,
                              hipStream_t stream) {
  (void)in_sizes; (void)n_in; (void)out_size;
  const float* s      = (const float*)d_in[0];
  const float* p      = (const float*)d_in[1];
  const float* adj    = (const float*)d_in[2];
  const float* sm1_Wi = (const float*)d_in[3];
  const float* sm1_Wh = (const float*)d_in[4];
  const float* sm1_bi = (const float*)d_in[5];
  const float* sm1_bh = (const float*)d_in[6];
  const float* sm2_Wi = (const float*)d_in[7];
  const float* sm2_Wh = (const float*)d_in[8];
  const float* sm2_bi = (const float*)d_in[9];
  const float* sm2_bh = (const float*)d_in[10];
  const float* pr_Wi  = (const float*)d_in[11];
  const float* pr_Wh  = (const float*)d_in[12];
  const float* pr_bi  = (const float*)d_in[13];
  const float* pr_bh  = (const float*)d_in[14];
  const float* Wb     = (const float*)d_in[15];
  const float* bb     = (const float*)d_in[16];
  const float* Wx     = (const float*)d_in[17];
  const float* bx     = (const float*)d_in[18];
  const float* W1     = (const float*)d_in[19];
  const float* a1     = (const float*)d_in[20];
  const float* W2     = (const float*)d_in[21];
  const float* a2     = (const float*)d_in[22];

  // workspace layout (bytes); total = 43,540,480
  if (ws_size < 43540480u) return;
  char* ws = (char*)d_ws;
  _Float16* gx1  = (_Float16*)ws;              // 39,321,600 (scan-layout fp16)
  _Float16* cvh  = (_Float16*)(ws + 39321600); // 655,360 (fp16 cv, [seq][t][64])
  float* ct      = (float*)(ws + 40632320);    // 262,144
  float* qt      = (float*)(ws + 40894464);    // 262,144
  float* X       = (float*)(ws + 41156608);    // 262,144
  float* X2      = (float*)(ws + 41418752);    // 2,097,152
  _Float16* Bt   = (_Float16*)(ws + 41418752); // 147,456 (dead before X2 written)

  hipLaunchKernelGGL(k_cvtB,     dim3(288),  dim3(256), 0, stream, sm1_Wi, Bt);
  hipLaunchKernelGGL(k_gx1,      dim3(800),  dim3(256), 0, stream, s, Bt, sm1_bi, gx1);
  hipLaunchKernelGGL(k_scan1m,   dim3(320),  dim3(64),  0, stream, gx1, sm1_Wh, sm1_bh, cvh);
  hipLaunchKernelGGL(k_scan23,   dim3(128),  dim3(64),  0, stream,
                     cvh, sm2_Wi, sm2_Wh, sm2_bi, sm2_bh, ct,
                     p, pr_Wi, pr_Wh, pr_bi, pr_bh, qt);
  hipLaunchKernelGGL(k_bilinear, dim3(256),  dim3(256), 0, stream, ct, qt, Wb, bb, X);
  hipLaunchKernelGGL(k_gat1,     dim3(128),  dim3(256), 0, stream, X, W1, a1, adj, X2);
  hipLaunchKernelGGL(k_head,     dim3(8),    dim3(256), 0, stream, X, Wx, bx, X2, W2, a2, adj, (float*)d_out);
}